// Round 1
// baseline (378.015 us; speedup 1.0000x reference)
//
#include <hip/hip_runtime.h>
#include <hip/hip_fp16.h>

#define N_NODES 50000
#define N_EDGES 400000
#define CSR_E (2 * N_EDGES + N_NODES) /* 850000 */
#define NCH 10        /* source chunks */
#define CHW 5000      /* chunk width: 5000 nodes * 256B = 1.28MB window */
#define NE2 (N_NODES * NCH) /* buckets: (node, chunk), node-major contiguous */

typedef unsigned short ushort_t;
typedef unsigned int uint_t;
typedef __attribute__((ext_vector_type(8))) short bf16x8;
typedef __attribute__((ext_vector_type(4))) float f32x4;

__device__ __forceinline__ float bf2f(ushort_t u) {
    return __uint_as_float(((uint_t)u) << 16);
}
__device__ __forceinline__ ushort_t f2bf(float f) {
    uint_t b = __float_as_uint(f);
    b += 0x7FFFu + ((b >> 16) & 1u); // RNE
    return (ushort_t)(b >> 16);
}
// fp16 pair packing for CSR entry weights (low = S-channel, high = D-channel)
__device__ __forceinline__ uint_t packw(float a, float b) {
    return ((uint_t)__half_as_ushort(__float2half(b)) << 16) |
           (uint_t)__half_as_ushort(__float2half(a));
}
__device__ __forceinline__ float unpl(uint_t w) {
    return __half2float(__ushort_as_half((ushort_t)(w & 0xffffu)));
}
__device__ __forceinline__ float unph(uint_t w) {
    return __half2float(__ushort_as_half((ushort_t)(w >> 16)));
}

// ---------------- static device scratch (module BSS; d_ws untouched) ----------------
// NOTE: only reference these from device code (host sees shadow addresses - r4 fault).

__device__ int g_est;  // edge-index word stride: 1 = int32, 2 = int64
__device__ int g_is16; // 1 = float tensors bf16-packed, 0 = fp32
__device__ __align__(8) float2 g_dis2[N_NODES]; // (dis_s, dis_r)
__device__ float g_degs[2 * N_NODES];           // (deg_s, deg_r) interleaved, f32 atomics
__device__ int g_cnt2[NE2];
__device__ int g_offs2[NE2 + 1];
__device__ uint_t g_rank[N_EDGES]; // low16 = fwd rank, high16 = rev rank
__device__ int g_bsum[512];
__device__ __align__(16) uint4 g_estage[N_EDGES]; // {s, r, c2 bits, s2 bits} staged by edge_cnt
__device__ __align__(16) uint2 g_csr8[CSR_E]; // {src, half2 w}: final (wS',wD') src-folded
__device__ __align__(16) ushort_t g_agg[(size_t)N_NODES * 256]; // bf16 [N][s128|d128]
__device__ __align__(16) ushort_t g_h1[(size_t)N_NODES * 128];  // bf16
__device__ __align__(16) ushort_t g_h2[(size_t)N_NODES * 128];  // bf16
__device__ __align__(16) ushort_t g_xcvt[(size_t)N_NODES * 128]; // bf16 (fp32-input fallback)
__device__ __align__(16) ushort_t g_bp1[8 * 128 * 32]; // B packed [kb][n][kk] bf16
__device__ __align__(16) ushort_t g_bp2[8 * 128 * 32];
__device__ __align__(16) ushort_t g_bp3[4 * 64 * 32];
__device__ float g_bc1[128];
__device__ float g_bc2[128];
__device__ float g_bro[64];

// ---------------- merged init: detect + cnt/deg init + fp32->bf16 convert ----------------
// Every block re-derives (is16, est) from the first 64 words via a wave-0 ballot
// (same 256B/512B broadcast reads, L2-serviced) so conversion can happen in the
// same launch without waiting on a global flag.

__global__ __launch_bounds__(256) void init_all(const uint_t* __restrict__ xw,
                                                const int* __restrict__ eidx,
                                                const float* __restrict__ x32) {
    __shared__ int s_flags;
    if (threadIdx.x < 64) {
        uint_t w = xw[threadIdx.x];
        int elo = (w >> 7) & 0xFF;
        unsigned long long mb = __ballot(elo >= 100 && elo <= 150);
        unsigned long long me = __ballot(eidx[2 * threadIdx.x + 1] != 0);
        if (threadIdx.x == 0) {
            int is16 = (__popcll(mb) >= 48) ? 1 : 0;
            int est = me ? 1 : 2;
            s_flags = is16 | (est << 1);
        }
    }
    __syncthreads();
    int is16 = s_flags & 1;
    int t = blockIdx.x * 256 + threadIdx.x;
    if (t == 0) {
        g_is16 = is16;
        g_est = s_flags >> 1;
    }
    if (t < N_NODES) {
        int sc = t / CHW;
#pragma unroll
        for (int c = 0; c < NCH; c++) g_cnt2[t * NCH + c] = (c == sc) ? 1 : 0; // self-loop slot
        g_degs[2 * t] = 0.f;
        g_degs[2 * t + 1] = 0.f;
    }
    if (!is16 && t < N_NODES * 128 / 8) {
        const float4* p = (const float4*)(x32 + t * 8);
        float4 a = p[0], b = p[1];
        ushort4 o0, o1;
        o0.x = f2bf(a.x); o0.y = f2bf(a.y); o0.z = f2bf(a.z); o0.w = f2bf(a.w);
        o1.x = f2bf(b.x); o1.y = f2bf(b.y); o1.z = f2bf(b.z); o1.w = f2bf(b.w);
        *(ushort4*)(g_xcvt + t * 8) = o0;
        *(ushort4*)(g_xcvt + t * 8 + 4) = o1;
    }
}

// ---------------- edge pass: ranks + degrees + staged (s,r,c2,s2) ----------------
// atomicAdd return value IS the bucket rank. Degrees accumulated here as f32
// atomics (deg_s[s]+=c2, deg_s[r]+=s2, deg_r[s]+=s2, deg_r[r]+=c2) so deg_pass
// and finalize_w are eliminated. sincos moved here - overlaps atomic latency.

__global__ __launch_bounds__(256) void edge_cnt(const int* __restrict__ eidx,
                                                const ushort_t* __restrict__ th16,
                                                const float* __restrict__ th32) {
    int e = blockIdx.x * 256 + threadIdx.x;
    if (e >= N_EDGES) return;
    int st = g_est;
    int s = eidx[(size_t)e * st];
    int r = eidx[((size_t)N_EDGES + e) * st];
    float t = g_is16 ? bf2f(th16[e]) : th32[e];
    float sn, cs_;
    sincosf(t, &sn, &cs_);
    float c2 = cs_ * cs_;
    float s2 = sn * sn;
    g_estage[e] = make_uint4((uint_t)s, (uint_t)r, __float_as_uint(c2), __float_as_uint(s2));
    int rf = atomicAdd(&g_cnt2[r * NCH + s / CHW], 1); // fwd: dst=r, chunk of s
    int rr = atomicAdd(&g_cnt2[s * NCH + r / CHW], 1); // rev: dst=s, chunk of r
    g_rank[e] = (uint_t)rf | ((uint_t)rr << 16);       // ranks < 65536 (max degree ~100)
    atomicAdd(&g_degs[2 * s], c2);
    atomicAdd(&g_degs[2 * s + 1], s2);
    atomicAdd(&g_degs[2 * r], s2);
    atomicAdd(&g_degs[2 * r + 1], c2);
}

// ---------------- scan phase 1: block scans + free-rider dis2 compute ----------------

__global__ __launch_bounds__(1024) void scan1() {
    int i = blockIdx.x * 1024 + threadIdx.x;
    if (i < N_NODES) { // degrees ready (edge_cnt done); +1 is the self-loop weight
        float ds = g_degs[2 * i];
        float dr = g_degs[2 * i + 1];
        g_dis2[i] = make_float2(rsqrtf(ds + 1.0f + 1e-12f), rsqrtf(dr + 1.0f + 1e-12f));
    }
    __shared__ int sd[1024];
    int v = (i < NE2) ? g_cnt2[i] : 0;
    sd[threadIdx.x] = v;
    __syncthreads();
    for (int o = 1; o < 1024; o <<= 1) {
        int tv = (threadIdx.x >= o) ? sd[threadIdx.x - o] : 0;
        __syncthreads();
        sd[threadIdx.x] += tv;
        __syncthreads();
    }
    if (i < NE2) g_offs2[i] = sd[threadIdx.x] - v;
    if (threadIdx.x == 1023) g_bsum[blockIdx.x] = sd[1023];
}

// ---------------- scan phase 2+3 merged: each block sums its bsum-prefix itself ----------------
// g_bsum is 2KB L2-resident broadcast; 489 blocks x <=489 reads is trivial, and it
// removes the single-block serialization + one launch.

__global__ __launch_bounds__(256) void scan23() {
    __shared__ int sd[256];
    int b = blockIdx.x;
    int acc = 0;
    for (int j = (int)threadIdx.x; j < b; j += 256) acc += g_bsum[j];
    sd[threadIdx.x] = acc;
    __syncthreads();
#pragma unroll
    for (int o = 128; o > 0; o >>= 1) {
        if ((int)threadIdx.x < o) sd[threadIdx.x] += sd[threadIdx.x + o];
        __syncthreads();
    }
    int base = sd[0];
    int i0 = b << 10;
#pragma unroll
    for (int u = 0; u < 4; u++) {
        int i = i0 + u * 256 + threadIdx.x;
        if (i < NE2) g_offs2[i] += base;
    }
    if (b == 0 && threadIdx.x == 0) g_offs2[NE2] = CSR_E; // sentinel
}

// ---------------- CSR fill: ZERO atomics, final src-folded weights in one rounding ----------------

__global__ __launch_bounds__(256) void fill_all() {
    int e = blockIdx.x * 256 + threadIdx.x;
    if (e < N_EDGES) {
        uint4 stg = g_estage[e];
        int s = (int)stg.x;
        int r = (int)stg.y;
        float c2 = __uint_as_float(stg.z);
        float s2 = __uint_as_float(stg.w);
        uint_t rk = g_rank[e];
        int pf = g_offs2[r * NCH + s / CHW] + (int)(rk & 0xffffu);
        int pr = g_offs2[s * NCH + r / CHW] + (int)(rk >> 16);
        float2 dss = g_dis2[s]; // (dis_s, dis_r) of s
        float2 dsr = g_dis2[r];
        // fwd entry (dst=r, src=s): out_w=c2, in_w=s2 -> wS'=dis_s[s]*c2, wD'=dis_r[s]*s2
        g_csr8[pf] = make_uint2((uint_t)s, packw(dss.x * c2, dss.y * s2));
        // rev entry (dst=s, src=r): out_w=s2, in_w=c2 -> wS'=dis_s[r]*s2, wD'=dis_r[r]*c2
        g_csr8[pr] = make_uint2((uint_t)r, packw(dsr.x * s2, dsr.y * c2));
    }
    if (e < N_NODES) { // self-loop at rank 0 of its bucket; out_w=in_w=1
        float2 d = g_dis2[e];
        g_csr8[g_offs2[e * NCH + e / CHW]] = make_uint2((uint_t)e, packw(d.x, d.y));
    }
}

// ---------------- weight prep (merged): Bp[kb][n][kk] bf16 + biases ----------------

__global__ __launch_bounds__(256) void prep_all(const ushort_t* W1s16, const float* W1s32,
                                                const ushort_t* W1d16, const float* W1d32,
                                                const ushort_t* b1s16, const float* b1s32,
                                                const ushort_t* b1d16, const float* b1d32,
                                                const ushort_t* W2s16, const float* W2s32,
                                                const ushort_t* W2d16, const float* W2d32,
                                                const ushort_t* b2s16, const float* b2s32,
                                                const ushort_t* b2d16, const float* b2d32,
                                                const ushort_t* Wro16, const float* Wro32,
                                                const ushort_t* bro16, const float* bro32) {
    int is16 = g_is16;
    int t = blockIdx.x * 256 + threadIdx.x;
    if (t < 2 * 32768) { // hidden layers
        int layer = t >> 15;
        int i = t & 32767;
        const ushort_t* Ws16 = layer ? W2s16 : W1s16;
        const float* Ws32 = layer ? W2s32 : W1s32;
        const ushort_t* Wd16 = layer ? W2d16 : W1d16;
        const float* Wd32 = layer ? W2d32 : W1d32;
        ushort_t* Bp = layer ? g_bp2 : g_bp1;
        int k = i >> 7, n = i & 127;
        ushort_t v;
        if (k < 128) {
            int idx = k * 128 + n;
            v = is16 ? Ws16[idx] : f2bf(Ws32[idx]);
        } else {
            int idx = (k - 128) * 128 + n;
            v = is16 ? Wd16[idx] : f2bf(Wd32[idx]);
        }
        int kb = k >> 5, kk = k & 31;
        Bp[((kb * 128 + n) << 5) + kk] = v;
        if (i < 128) {
            const ushort_t* bs16 = layer ? b2s16 : b1s16;
            const float* bs32 = layer ? b2s32 : b1s32;
            const ushort_t* bd16 = layer ? b2d16 : b1d16;
            const float* bd32 = layer ? b2d32 : b1d32;
            float a = is16 ? bf2f(bs16[i]) : bs32[i];
            float b = is16 ? bf2f(bd16[i]) : bd32[i];
            (layer ? g_bc2 : g_bc1)[i] = 0.5f * (a + b);
        }
    } else if (t < 2 * 32768 + 8192) { // readout
        int i = t - 2 * 32768;
        int k = i >> 6, n = i & 63;
        ushort_t v = is16 ? Wro16[i] : f2bf(Wro32[i]);
        int kb = k >> 5, kk = k & 31;
        g_bp3[((kb * 64 + n) << 5) + kk] = v;
        if (i < 64) g_bro[i] = is16 ? bf2f(bro16[i]) : bro32[i];
    }
}

// ---------------- gang-gather aggregation (8B entries, dst-factor epilogue) ----------------
// 16-lane group owns one node; lane r loads 16B (8 bf16) of the entry row via
// dwordx4 -> 4 entries serviced per gather instruction. Entries are 8B
// {src, half2(wS',wD')} with src-dis pre-folded; epilogue applies
// 0.5*dis_r[n] (S) and 0.5*dis_s[n] (D). Buckets node-major, chunk-sorted
// interior -> contiguous per-node range, soft-lockstep L2 window.

__global__ __launch_bounds__(256) void aggregate_gang(const ushort_t* __restrict__ xext, int ext) {
    int w = threadIdx.x >> 6;
    int lane = threadIdx.x & 63;
    int gsel = lane >> 4; // which of the wave's 4 nodes
    int r = lane & 15;    // feature sub-block: feats 8r..8r+7
    int node = (blockIdx.x * 4 + w) * 4 + gsel; // 3125 blocks * 16 nodes, exact
    const ushort_t* xin = ext ? (g_is16 ? xext : g_xcvt) : g_h1;

    int ks = g_offs2[node * NCH];
    int ke = g_offs2[node * NCH + NCH];
    int c = ke - ks;
    int cmax = c;
    cmax = max(cmax, __shfl_xor(cmax, 16));
    cmax = max(cmax, __shfl_xor(cmax, 32));

    float accS[8], accD[8];
#pragma unroll
    for (int f = 0; f < 8; f++) { accS[f] = 0.f; accD[f] = 0.f; }

    int k = 0;
    for (; k + 2 <= cmax; k += 2) {
        int i0 = ks + min(k, c - 1);
        int i1 = ks + min(k + 1, c - 1);
        uint2 e0 = g_csr8[i0];
        uint2 e1 = g_csr8[i1];
        bf16x8 v0 = *(const bf16x8*)(xin + (size_t)e0.x * 128 + r * 8);
        bf16x8 v1 = *(const bf16x8*)(xin + (size_t)e1.x * 128 + r * 8);
        float w0s = (k < c) ? unpl(e0.y) : 0.f;
        float w0d = (k < c) ? unph(e0.y) : 0.f;
        float w1s = (k + 1 < c) ? unpl(e1.y) : 0.f;
        float w1d = (k + 1 < c) ? unph(e1.y) : 0.f;
#pragma unroll
        for (int f = 0; f < 8; f++) {
            float x0 = bf2f((ushort_t)v0[f]);
            float x1 = bf2f((ushort_t)v1[f]);
            accS[f] = fmaf(w0s, x0, accS[f]);
            accD[f] = fmaf(w0d, x0, accD[f]);
            accS[f] = fmaf(w1s, x1, accS[f]);
            accD[f] = fmaf(w1d, x1, accD[f]);
        }
    }
    if (k < cmax) {
        int i0 = ks + min(k, c - 1);
        uint2 e0 = g_csr8[i0];
        bf16x8 v0 = *(const bf16x8*)(xin + (size_t)e0.x * 128 + r * 8);
        float w0s = (k < c) ? unpl(e0.y) : 0.f;
        float w0d = (k < c) ? unph(e0.y) : 0.f;
#pragma unroll
        for (int f = 0; f < 8; f++) {
            float x0 = bf2f((ushort_t)v0[f]);
            accS[f] = fmaf(w0s, x0, accS[f]);
            accD[f] = fmaf(w0d, x0, accD[f]);
        }
    }

    float2 dn = g_dis2[node];
    float fs = 0.5f * dn.y; // S channel: 0.5 * dis_r[dst]
    float fd = 0.5f * dn.x; // D channel: 0.5 * dis_s[dst]
    uint_t oS[4], oD[4];
#pragma unroll
    for (int p = 0; p < 4; p++) {
        oS[p] = ((uint_t)f2bf(accS[2 * p + 1] * fs) << 16) | (uint_t)f2bf(accS[2 * p] * fs);
        oD[p] = ((uint_t)f2bf(accD[2 * p + 1] * fd) << 16) | (uint_t)f2bf(accD[2 * p] * fd);
    }
    *(uint4*)(g_agg + (size_t)node * 256 + r * 8) = make_uint4(oS[0], oS[1], oS[2], oS[3]);
    *(uint4*)(g_agg + (size_t)node * 256 + 128 + r * 8) = make_uint4(oD[0], oD[1], oD[2], oD[3]);
}

// ---------------- MFMA GEMM: C = act(A[M][K]bf16 @ B + bias) ----------------
// LAYER 0: g_h1 = relu(g_agg @ g_bp1 + g_bc1), K=256, N=128
// LAYER 1: g_h2 = relu(g_agg @ g_bp2 + g_bc2), K=256, N=128
// LAYER 2: out  = g_h2 @ g_bp3 + g_bro, K=128, N=64 (dtype-flex store to outp)
// Verified layouts: A[m=lane&15][k=(lane>>4)*8+j]; B[k=(lane>>4)*8+j][n=lane&15];
//                   C col=lane&15, row=(lane>>4)*4+reg.

template <int LAYER, int KB, int NN, int NT, int RELU>
__global__ __launch_bounds__(256) void gemm_mfma(void* __restrict__ outp) {
    const ushort_t* A = (LAYER == 2) ? g_h2 : g_agg;
    const ushort_t* Bp = (LAYER == 0) ? g_bp1 : (LAYER == 1) ? g_bp2 : g_bp3;
    const float* bias = (LAYER == 0) ? g_bc1 : (LAYER == 1) ? g_bc2 : g_bro;
    const int M = N_NODES;
    const int K = KB * 32;
    int w = threadIdx.x >> 6; // wave 0..3
    int lane = threadIdx.x & 63;
    int c = lane & 15;
    int q = lane >> 4;
    int mBase = blockIdx.x * 64 + w * 16;

    f32x4 acc[NT];
#pragma unroll
    for (int nt = 0; nt < NT; nt++) acc[nt] = {0.f, 0.f, 0.f, 0.f};

    int arow = mBase + c;
    if (arow >= M) arow = M - 1; // clamp; stores guarded

#pragma unroll
    for (int kb = 0; kb < KB; kb++) {
        bf16x8 a = *(const bf16x8*)(A + (size_t)arow * K + kb * 32 + q * 8);
#pragma unroll
        for (int nt = 0; nt < NT; nt++) {
            bf16x8 b = *(const bf16x8*)(Bp + (((kb * NN + nt * 16 + c) << 5) + q * 8));
            acc[nt] = __builtin_amdgcn_mfma_f32_16x16x32_bf16(a, b, acc[nt], 0, 0, 0);
        }
    }

    int is16 = (LAYER == 2) ? g_is16 : 1;
#pragma unroll
    for (int nt = 0; nt < NT; nt++) {
        int n = nt * 16 + c;
        float bi = bias[n];
#pragma unroll
        for (int r = 0; r < 4; r++) {
            int m = mBase + q * 4 + r;
            if (m >= M) continue;
            float v = acc[nt][r] + bi;
            if (RELU) v = fmaxf(v, 0.f);
            if (LAYER == 0)
                g_h1[(size_t)m * NN + n] = f2bf(v);
            else if (LAYER == 1)
                g_h2[(size_t)m * NN + n] = f2bf(v);
            else if (is16)
                ((ushort_t*)outp)[(size_t)m * NN + n] = f2bf(v);
            else
                ((float*)outp)[(size_t)m * NN + n] = v;
        }
    }
}

// ---------------- launch ----------------

static inline int cdiv(int a, int b) { return (a + b - 1) / b; }

extern "C" void kernel_launch(void* const* d_in, const int* in_sizes, int n_in,
                              void* d_out, int out_size, void* d_ws, size_t ws_size,
                              hipStream_t stream) {
    const void* x = d_in[0]; // [50000][128]
    const int* eidx = (const int*)d_in[1];
    const void* theta = d_in[2];
    const void* W1s = d_in[3];
    const void* W1d = d_in[4];
    const void* b1s = d_in[5];
    const void* b1d = d_in[6];
    const void* W2s = d_in[7];
    const void* W2d = d_in[8];
    const void* b2s = d_in[9];
    const void* b2d = d_in[10];
    const void* Wro = d_in[11];
    const void* bro = d_in[12];
    (void)in_sizes; (void)n_in; (void)out_size; (void)d_ws; (void)ws_size;

    const int NB2 = cdiv(NE2, 1024); // 489

    init_all<<<cdiv(N_NODES * 128 / 8, 256), 256, 0, stream>>>(
        (const uint_t*)x, eidx, (const float*)x);
    edge_cnt<<<cdiv(N_EDGES, 256), 256, 0, stream>>>(
        eidx, (const ushort_t*)theta, (const float*)theta);
    scan1<<<NB2, 1024, 0, stream>>>();
    scan23<<<NB2, 256, 0, stream>>>();
    fill_all<<<cdiv(N_EDGES, 256), 256, 0, stream>>>();
    prep_all<<<cdiv(2 * 32768 + 8192, 256), 256, 0, stream>>>(
        (const ushort_t*)W1s, (const float*)W1s, (const ushort_t*)W1d, (const float*)W1d,
        (const ushort_t*)b1s, (const float*)b1s, (const ushort_t*)b1d, (const float*)b1d,
        (const ushort_t*)W2s, (const float*)W2s, (const ushort_t*)W2d, (const float*)W2d,
        (const ushort_t*)b2s, (const float*)b2s, (const ushort_t*)b2d, (const float*)b2d,
        (const ushort_t*)Wro, (const float*)Wro, (const ushort_t*)bro, (const float*)bro);

    const int AB = N_NODES / 16; // 3125 blocks, 16 nodes each (exact)
    const int GB = cdiv(N_NODES, 64); // 782
    // layer 1
    aggregate_gang<<<AB, 256, 0, stream>>>((const ushort_t*)x, 1);
    gemm_mfma<0, 8, 128, 8, 1><<<GB, 256, 0, stream>>>(nullptr);
    // layer 2
    aggregate_gang<<<AB, 256, 0, stream>>>(nullptr, 0);
    gemm_mfma<1, 8, 128, 8, 1><<<GB, 256, 0, stream>>>(nullptr);
    // readout
    gemm_mfma<2, 4, 64, 4, 0><<<GB, 256, 0, stream>>>(d_out);
}

// Round 2
// 272.654 us; speedup vs baseline: 1.3864x; 1.3864x over previous
//
#include <hip/hip_runtime.h>
#include <hip/hip_fp16.h>

#define N_NODES 50000
#define N_EDGES 400000
#define CSR_E (2 * N_EDGES + N_NODES) /* 850000 */
#define NCH 10        /* source chunks */
#define CHW 5000      /* chunk width: 5000 nodes * 256B = 1.28MB window */
#define NE2 (N_NODES * NCH) /* buckets: (node, chunk), node-major contiguous */

typedef unsigned short ushort_t;
typedef unsigned int uint_t;
typedef __attribute__((ext_vector_type(8))) short bf16x8;
typedef __attribute__((ext_vector_type(4))) float f32x4;

__device__ __forceinline__ float bf2f(ushort_t u) {
    return __uint_as_float(((uint_t)u) << 16);
}
__device__ __forceinline__ ushort_t f2bf(float f) {
    uint_t b = __float_as_uint(f);
    b += 0x7FFFu + ((b >> 16) & 1u); // RNE
    return (ushort_t)(b >> 16);
}
// fp16 pair packing for CSR entry weights (low = S-channel, high = D-channel)
__device__ __forceinline__ uint_t packw(float a, float b) {
    return ((uint_t)__half_as_ushort(__float2half(b)) << 16) |
           (uint_t)__half_as_ushort(__float2half(a));
}
__device__ __forceinline__ float unpl(uint_t w) {
    return __half2float(__ushort_as_half((ushort_t)(w & 0xffffu)));
}
__device__ __forceinline__ float unph(uint_t w) {
    return __half2float(__ushort_as_half((ushort_t)(w >> 16)));
}

// ---------------- static device scratch (module BSS; d_ws untouched) ----------------
// NOTE: only reference these from device code (host sees shadow addresses - r4 fault).

__device__ int g_est;  // edge-index word stride: 1 = int32, 2 = int64
__device__ int g_is16; // 1 = float tensors bf16-packed, 0 = fp32
__device__ __align__(8) float2 g_dis2[N_NODES]; // (dis_s, dis_r)
__device__ int g_cnt2[NE2];
__device__ int g_offs2[NE2 + 1];
__device__ uint_t g_rank[N_EDGES]; // low16 = fwd rank, high16 = rev rank
__device__ int g_bsum[512];
__device__ __align__(16) uint4 g_estage[N_EDGES]; // {s, r, c2 bits, s2 bits} staged by edge_cnt
__device__ __align__(16) uint2 g_csr8[CSR_E]; // {src, half2 w}: raw (out,in) -> final (wS',wD') src-folded
__device__ __align__(16) ushort_t g_h1[(size_t)N_NODES * 128];  // bf16
__device__ __align__(16) ushort_t g_xcvt[(size_t)N_NODES * 128]; // bf16 (fp32-input fallback)
__device__ __align__(16) ushort_t g_bp1[8 * 128 * 32]; // B packed [kb][n][kk] bf16
__device__ __align__(16) ushort_t g_bp2[8 * 128 * 32];
__device__ __align__(16) ushort_t g_bp3[4 * 64 * 32];
__device__ float g_bc1[128];
__device__ float g_bc2[128];
__device__ float g_bro[64];

// ---------------- merged init: detect + cnt init + fp32->bf16 convert ----------------
// Every block re-derives (is16, est) from the first 64 words via a wave-0 ballot
// (broadcast reads, L2-serviced) so conversion can happen in the same launch.

__global__ __launch_bounds__(256) void init_all(const uint_t* __restrict__ xw,
                                                const int* __restrict__ eidx,
                                                const float* __restrict__ x32) {
    __shared__ int s_flags;
    if (threadIdx.x < 64) {
        uint_t w = xw[threadIdx.x];
        int elo = (w >> 7) & 0xFF;
        unsigned long long mb = __ballot(elo >= 100 && elo <= 150);
        unsigned long long me = __ballot(eidx[2 * threadIdx.x + 1] != 0);
        if (threadIdx.x == 0) {
            int is16 = (__popcll(mb) >= 48) ? 1 : 0;
            int est = me ? 1 : 2;
            s_flags = is16 | (est << 1);
        }
    }
    __syncthreads();
    int is16 = s_flags & 1;
    int t = blockIdx.x * 256 + threadIdx.x;
    if (t == 0) {
        g_is16 = is16;
        g_est = s_flags >> 1;
    }
    if (t < N_NODES) {
        int sc = t / CHW;
#pragma unroll
        for (int c = 0; c < NCH; c++) g_cnt2[t * NCH + c] = (c == sc) ? 1 : 0; // self-loop slot
    }
    if (!is16 && t < N_NODES * 128 / 8) {
        const float4* p = (const float4*)(x32 + t * 8);
        float4 a = p[0], b = p[1];
        ushort4 o0, o1;
        o0.x = f2bf(a.x); o0.y = f2bf(a.y); o0.z = f2bf(a.z); o0.w = f2bf(a.w);
        o1.x = f2bf(b.x); o1.y = f2bf(b.y); o1.z = f2bf(b.z); o1.w = f2bf(b.w);
        *(ushort4*)(g_xcvt + t * 8) = o0;
        *(ushort4*)(g_xcvt + t * 8 + 4) = o1;
    }
}

// ---------------- edge pass: ranks + staged (s,r,c2,s2). NO degree atomics ----------------
// (r1 post-mortem: 4 scattered f32 atomics/edge cost +85us and 82MB of HBM
// write-back; degrees via contiguous CSR read in deg_pass are ~10us total.)

__global__ __launch_bounds__(256) void edge_cnt(const int* __restrict__ eidx,
                                                const ushort_t* __restrict__ th16,
                                                const float* __restrict__ th32) {
    int e = blockIdx.x * 256 + threadIdx.x;
    if (e >= N_EDGES) return;
    int st = g_est;
    int s = eidx[(size_t)e * st];
    int r = eidx[((size_t)N_EDGES + e) * st];
    float t = g_is16 ? bf2f(th16[e]) : th32[e];
    float sn, cs_;
    sincosf(t, &sn, &cs_);
    float c2 = cs_ * cs_;
    float s2 = sn * sn;
    g_estage[e] = make_uint4((uint_t)s, (uint_t)r, __float_as_uint(c2), __float_as_uint(s2));
    int rf = atomicAdd(&g_cnt2[r * NCH + s / CHW], 1); // fwd: dst=r, chunk of s
    int rr = atomicAdd(&g_cnt2[s * NCH + r / CHW], 1); // rev: dst=s, chunk of r
    g_rank[e] = (uint_t)rf | ((uint_t)rr << 16);       // ranks < 65536 (max degree ~100)
}

// ---------------- scan phase 1: per-block inclusive scans ----------------

__global__ __launch_bounds__(1024) void scan1() {
    __shared__ int sd[1024];
    int i = blockIdx.x * 1024 + threadIdx.x;
    int v = (i < NE2) ? g_cnt2[i] : 0;
    sd[threadIdx.x] = v;
    __syncthreads();
    for (int o = 1; o < 1024; o <<= 1) {
        int tv = (threadIdx.x >= o) ? sd[threadIdx.x - o] : 0;
        __syncthreads();
        sd[threadIdx.x] += tv;
        __syncthreads();
    }
    if (i < NE2) g_offs2[i] = sd[threadIdx.x] - v;
    if (threadIdx.x == 1023) g_bsum[blockIdx.x] = sd[1023];
}

// ---------------- scan phase 2+3 merged: each block sums its bsum-prefix itself ----------------

__global__ __launch_bounds__(256) void scan23() {
    __shared__ int sd[256];
    int b = blockIdx.x;
    int acc = 0;
    for (int j = (int)threadIdx.x; j < b; j += 256) acc += g_bsum[j];
    sd[threadIdx.x] = acc;
    __syncthreads();
#pragma unroll
    for (int o = 128; o > 0; o >>= 1) {
        if ((int)threadIdx.x < o) sd[threadIdx.x] += sd[threadIdx.x + o];
        __syncthreads();
    }
    int base = sd[0];
    int i0 = b << 10;
#pragma unroll
    for (int u = 0; u < 4; u++) {
        int i = i0 + u * 256 + threadIdx.x;
        if (i < NE2) g_offs2[i] += base;
    }
    if (b == 0 && threadIdx.x == 0) g_offs2[NE2] = CSR_E; // sentinel
}

// ---------------- CSR fill from staged edges: ZERO atomics, raw weights ----------------

__global__ __launch_bounds__(256) void fill_all() {
    int e = blockIdx.x * 256 + threadIdx.x;
    if (e < N_EDGES) {
        uint4 stg = g_estage[e];
        int s = (int)stg.x;
        int r = (int)stg.y;
        float c2 = __uint_as_float(stg.z);
        float s2 = __uint_as_float(stg.w);
        uint_t rk = g_rank[e];
        int pf = g_offs2[r * NCH + s / CHW] + (int)(rk & 0xffffu);
        int pr = g_offs2[s * NCH + r / CHW] + (int)(rk >> 16);
        g_csr8[pf] = make_uint2((uint_t)s, packw(c2, s2)); // fwd: cs=s, out=c2, in=s2
        g_csr8[pr] = make_uint2((uint_t)r, packw(s2, c2)); // rev: cs=r, out=s2, in=c2
    }
    if (e < N_NODES) { // self-loop at rank 0 of its bucket
        g_csr8[g_offs2[e * NCH + e / CHW]] = make_uint2((uint_t)e, packw(1.0f, 1.0f));
    }
}

// ---------------- degrees (atomic-free; contiguous per-node range) ----------------

__global__ __launch_bounds__(256) void deg_pass() {
    int n = blockIdx.x * 256 + threadIdx.x;
    if (n >= N_NODES) return;
    int kb = g_offs2[n * NCH];
    int ke = g_offs2[n * NCH + NCH];
    float ds = 0.f, dr = 0.f;
    for (int k = kb; k < ke; k++) {
        uint_t w = g_csr8[k].y;
        ds += unph(w); // in_w
        dr += unpl(w); // out_w
    }
    g_dis2[n] = make_float2(rsqrtf(ds + 1e-12f), rsqrtf(dr + 1e-12f));
}

// ---------------- finalize: fold SRC factors only (dst folded in agg epilogue) ----------------

__global__ __launch_bounds__(256) void finalize_w() {
    int i = blockIdx.x * 256 + threadIdx.x;
    if (i >= CSR_E) return;
    uint2 e = g_csr8[i];
    float2 d = g_dis2[e.x]; // (dis_s, dis_r) of src
    ((uint_t*)g_csr8)[2 * (size_t)i + 1] = packw(d.x * unpl(e.y), d.y * unph(e.y));
}

// ---------------- weight prep (merged): Bp[kb][n][kk] bf16 + biases ----------------

__global__ __launch_bounds__(256) void prep_all(const ushort_t* W1s16, const float* W1s32,
                                                const ushort_t* W1d16, const float* W1d32,
                                                const ushort_t* b1s16, const float* b1s32,
                                                const ushort_t* b1d16, const float* b1d32,
                                                const ushort_t* W2s16, const float* W2s32,
                                                const ushort_t* W2d16, const float* W2d32,
                                                const ushort_t* b2s16, const float* b2s32,
                                                const ushort_t* b2d16, const float* b2d32,
                                                const ushort_t* Wro16, const float* Wro32,
                                                const ushort_t* bro16, const float* bro32) {
    int is16 = g_is16;
    int t = blockIdx.x * 256 + threadIdx.x;
    if (t < 2 * 32768) { // hidden layers
        int layer = t >> 15;
        int i = t & 32767;
        const ushort_t* Ws16 = layer ? W2s16 : W1s16;
        const float* Ws32 = layer ? W2s32 : W1s32;
        const ushort_t* Wd16 = layer ? W2d16 : W1d16;
        const float* Wd32 = layer ? W2d32 : W1d32;
        ushort_t* Bp = layer ? g_bp2 : g_bp1;
        int k = i >> 7, n = i & 127;
        ushort_t v;
        if (k < 128) {
            int idx = k * 128 + n;
            v = is16 ? Ws16[idx] : f2bf(Ws32[idx]);
        } else {
            int idx = (k - 128) * 128 + n;
            v = is16 ? Wd16[idx] : f2bf(Wd32[idx]);
        }
        int kb = k >> 5, kk = k & 31;
        Bp[((kb * 128 + n) << 5) + kk] = v;
        if (i < 128) {
            const ushort_t* bs16 = layer ? b2s16 : b1s16;
            const float* bs32 = layer ? b2s32 : b1s32;
            const ushort_t* bd16 = layer ? b2d16 : b1d16;
            const float* bd32 = layer ? b2d32 : b1d32;
            float a = is16 ? bf2f(bs16[i]) : bs32[i];
            float b = is16 ? bf2f(bd16[i]) : bd32[i];
            (layer ? g_bc2 : g_bc1)[i] = 0.5f * (a + b);
        }
    } else if (t < 2 * 32768 + 8192) { // readout
        int i = t - 2 * 32768;
        int k = i >> 6, n = i & 63;
        ushort_t v = is16 ? Wro16[i] : f2bf(Wro32[i]);
        int kb = k >> 5, kk = k & 31;
        g_bp3[((kb * 64 + n) << 5) + kk] = v;
        if (i < 64) g_bro[i] = is16 ? bf2f(bro16[i]) : bro32[i];
    }
}

// ---------------- FUSED layer: gang-gather aggregation -> LDS tile -> MFMA GEMM ----------------
// Block = 256 threads = 16 nodes (grid 3125, exact). Phase A is the verified
// aggregate_gang body; epilogue writes the bf16 [16][256] tile to LDS with the
// T2 XOR swizzle (byte ^= (row&7)<<4) instead of a g_agg HBM round-trip.
// Phase B: 4 waves x 32 output cols, KB=8 x NT=2 MFMA on the LDS tile
// (verified layouts: A[m=lane&15][k=(lane>>4)*8+j]; C col=lane&15,
// row=(lane>>4)*4+reg). LAYER 0 stores relu(..) to g_h1; LAYER 1 keeps h2 in
// a second LDS tile and runs the readout GEMM (K=128, N=64) in the same block.

template <int LAYER>
__global__ __launch_bounds__(256) void fused_layer(const ushort_t* __restrict__ xext,
                                                   void* __restrict__ outp) {
    __shared__ ushort_t tA[16 * 256];                       // agg tile, swizzled
    __shared__ ushort_t tH[(LAYER == 1) ? 16 * 128 : 1];    // h2 tile (L1 only)
    int w = threadIdx.x >> 6;
    int lane = threadIdx.x & 63;
    int gsel = lane >> 4; // which of the wave's 4 nodes
    int r = lane & 15;    // feature sub-block: feats 8r..8r+7
    int lrow = w * 4 + gsel;            // local row 0..15
    int node = blockIdx.x * 16 + lrow;  // exact: 3125*16 = 50000
    const ushort_t* xin = (LAYER == 0) ? (g_is16 ? xext : g_xcvt) : g_h1;

    int ks = g_offs2[node * NCH];
    int ke = g_offs2[node * NCH + NCH];
    int c0 = ke - ks;
    int cmax = c0;
    cmax = max(cmax, __shfl_xor(cmax, 16));
    cmax = max(cmax, __shfl_xor(cmax, 32));

    float accS[8], accD[8];
#pragma unroll
    for (int f = 0; f < 8; f++) { accS[f] = 0.f; accD[f] = 0.f; }

    int k = 0;
    for (; k + 2 <= cmax; k += 2) {
        int i0 = ks + min(k, c0 - 1);
        int i1 = ks + min(k + 1, c0 - 1);
        uint2 e0 = g_csr8[i0];
        uint2 e1 = g_csr8[i1];
        bf16x8 v0 = *(const bf16x8*)(xin + (size_t)e0.x * 128 + r * 8);
        bf16x8 v1 = *(const bf16x8*)(xin + (size_t)e1.x * 128 + r * 8);
        float w0s = (k < c0) ? unpl(e0.y) : 0.f;
        float w0d = (k < c0) ? unph(e0.y) : 0.f;
        float w1s = (k + 1 < c0) ? unpl(e1.y) : 0.f;
        float w1d = (k + 1 < c0) ? unph(e1.y) : 0.f;
#pragma unroll
        for (int f = 0; f < 8; f++) {
            float x0 = bf2f((ushort_t)v0[f]);
            float x1 = bf2f((ushort_t)v1[f]);
            accS[f] = fmaf(w0s, x0, accS[f]);
            accD[f] = fmaf(w0d, x0, accD[f]);
            accS[f] = fmaf(w1s, x1, accS[f]);
            accD[f] = fmaf(w1d, x1, accD[f]);
        }
    }
    if (k < cmax) {
        int i0 = ks + min(k, c0 - 1);
        uint2 e0 = g_csr8[i0];
        bf16x8 v0 = *(const bf16x8*)(xin + (size_t)e0.x * 128 + r * 8);
        float w0s = (k < c0) ? unpl(e0.y) : 0.f;
        float w0d = (k < c0) ? unph(e0.y) : 0.f;
#pragma unroll
        for (int f = 0; f < 8; f++) {
            float x0 = bf2f((ushort_t)v0[f]);
            accS[f] = fmaf(w0s, x0, accS[f]);
            accD[f] = fmaf(w0d, x0, accD[f]);
        }
    }

    float2 dn = g_dis2[node];
    float fs = 0.5f * dn.y; // S channel: 0.5 * dis_r[dst]
    float fd = 0.5f * dn.x; // D channel: 0.5 * dis_s[dst]
    uint_t oS[4], oD[4];
#pragma unroll
    for (int p = 0; p < 4; p++) {
        oS[p] = ((uint_t)f2bf(accS[2 * p + 1] * fs) << 16) | (uint_t)f2bf(accS[2 * p] * fs);
        oD[p] = ((uint_t)f2bf(accD[2 * p + 1] * fd) << 16) | (uint_t)f2bf(accD[2 * p] * fd);
    }
    int swA = (lrow & 7) << 4;
    *(uint4*)((char*)tA + ((lrow * 512 + r * 16) ^ swA)) = make_uint4(oS[0], oS[1], oS[2], oS[3]);
    *(uint4*)((char*)tA + ((lrow * 512 + 256 + r * 16) ^ swA)) = make_uint4(oD[0], oD[1], oD[2], oD[3]);
    __syncthreads();

    // ---- phase B: GEMM on the 16-row tile; wave w owns cols w*32..w*32+31 ----
    int cc = lane & 15;
    int q = lane >> 4;
    int csw = (cc & 7) << 4;
    const ushort_t* Bp = (LAYER == 0) ? g_bp1 : g_bp2;
    const float* bias = (LAYER == 0) ? g_bc1 : g_bc2;
    f32x4 acc0 = {0.f, 0.f, 0.f, 0.f};
    f32x4 acc1 = {0.f, 0.f, 0.f, 0.f};
#pragma unroll
    for (int kb = 0; kb < 8; kb++) {
        bf16x8 a = *(const bf16x8*)((const char*)tA + ((cc * 512 + kb * 64 + q * 16) ^ csw));
        bf16x8 b0 = *(const bf16x8*)(Bp + (((kb * 128 + w * 32 + cc) << 5) + q * 8));
        bf16x8 b1 = *(const bf16x8*)(Bp + (((kb * 128 + w * 32 + 16 + cc) << 5) + q * 8));
        acc0 = __builtin_amdgcn_mfma_f32_16x16x32_bf16(a, b0, acc0, 0, 0, 0);
        acc1 = __builtin_amdgcn_mfma_f32_16x16x32_bf16(a, b1, acc1, 0, 0, 0);
    }
    int mb = blockIdx.x * 16;
    float bi0 = bias[w * 32 + cc];
    float bi1 = bias[w * 32 + 16 + cc];
    if (LAYER == 0) {
#pragma unroll
        for (int rr = 0; rr < 4; rr++) {
            int m = mb + q * 4 + rr;
            g_h1[(size_t)m * 128 + w * 32 + cc] = f2bf(fmaxf(acc0[rr] + bi0, 0.f));
            g_h1[(size_t)m * 128 + w * 32 + 16 + cc] = f2bf(fmaxf(acc1[rr] + bi1, 0.f));
        }
    } else {
#pragma unroll
        for (int rr = 0; rr < 4; rr++) {
            int ml = q * 4 + rr;
            int msw = (ml & 7) << 4;
            *(ushort_t*)((char*)tH + ((ml * 256 + (w * 32 + cc) * 2) ^ msw)) =
                f2bf(fmaxf(acc0[rr] + bi0, 0.f));
            *(ushort_t*)((char*)tH + ((ml * 256 + (w * 32 + 16 + cc) * 2) ^ msw)) =
                f2bf(fmaxf(acc1[rr] + bi1, 0.f));
        }
        __syncthreads();
        // ---- phase C: readout GEMM, K=128, N=64; wave w owns cols w*16..w*16+15 ----
        f32x4 a3 = {0.f, 0.f, 0.f, 0.f};
#pragma unroll
        for (int kb = 0; kb < 4; kb++) {
            bf16x8 a = *(const bf16x8*)((const char*)tH + ((cc * 256 + kb * 64 + q * 16) ^ csw));
            bf16x8 b = *(const bf16x8*)(g_bp3 + (((kb * 64 + w * 16 + cc) << 5) + q * 8));
            a3 = __builtin_amdgcn_mfma_f32_16x16x32_bf16(a, b, a3, 0, 0, 0);
        }
        int is16 = g_is16;
        float bi = g_bro[w * 16 + cc];
#pragma unroll
        for (int rr = 0; rr < 4; rr++) {
            int m = mb + q * 4 + rr;
            float v = a3[rr] + bi;
            if (is16)
                ((ushort_t*)outp)[(size_t)m * 64 + w * 16 + cc] = f2bf(v);
            else
                ((float*)outp)[(size_t)m * 64 + w * 16 + cc] = v;
        }
    }
}

// ---------------- launch ----------------

static inline int cdiv(int a, int b) { return (a + b - 1) / b; }

extern "C" void kernel_launch(void* const* d_in, const int* in_sizes, int n_in,
                              void* d_out, int out_size, void* d_ws, size_t ws_size,
                              hipStream_t stream) {
    const void* x = d_in[0]; // [50000][128]
    const int* eidx = (const int*)d_in[1];
    const void* theta = d_in[2];
    const void* W1s = d_in[3];
    const void* W1d = d_in[4];
    const void* b1s = d_in[5];
    const void* b1d = d_in[6];
    const void* W2s = d_in[7];
    const void* W2d = d_in[8];
    const void* b2s = d_in[9];
    const void* b2d = d_in[10];
    const void* Wro = d_in[11];
    const void* bro = d_in[12];
    (void)in_sizes; (void)n_in; (void)out_size; (void)d_ws; (void)ws_size;

    const int NB2 = cdiv(NE2, 1024); // 489

    init_all<<<cdiv(N_NODES * 128 / 8, 256), 256, 0, stream>>>(
        (const uint_t*)x, eidx, (const float*)x);
    edge_cnt<<<cdiv(N_EDGES, 256), 256, 0, stream>>>(
        eidx, (const ushort_t*)theta, (const float*)theta);
    scan1<<<NB2, 1024, 0, stream>>>();
    scan23<<<NB2, 256, 0, stream>>>();
    fill_all<<<cdiv(N_EDGES, 256), 256, 0, stream>>>();
    deg_pass<<<cdiv(N_NODES, 256), 256, 0, stream>>>();
    finalize_w<<<cdiv(CSR_E, 256), 256, 0, stream>>>();
    prep_all<<<cdiv(2 * 32768 + 8192, 256), 256, 0, stream>>>(
        (const ushort_t*)W1s, (const float*)W1s, (const ushort_t*)W1d, (const float*)W1d,
        (const ushort_t*)b1s, (const float*)b1s, (const ushort_t*)b1d, (const float*)b1d,
        (const ushort_t*)W2s, (const float*)W2s, (const ushort_t*)W2d, (const float*)W2d,
        (const ushort_t*)b2s, (const float*)b2s, (const ushort_t*)b2d, (const float*)b2d,
        (const ushort_t*)Wro, (const float*)Wro, (const ushort_t*)bro, (const float*)bro);

    const int AB = N_NODES / 16; // 3125 blocks, 16 nodes each (exact)
    fused_layer<0><<<AB, 256, 0, stream>>>((const ushort_t*)x, nullptr);
    fused_layer<1><<<AB, 256, 0, stream>>>(nullptr, d_out);
}

// Round 4
// 272.085 us; speedup vs baseline: 1.3893x; 1.0021x over previous
//
#include <hip/hip_runtime.h>
#include <hip/hip_fp16.h>

#define N_NODES 50000
#define N_EDGES 400000
#define CSR_E (2 * N_EDGES + N_NODES) /* 850000 */
#define NCH 10        /* source chunks */
#define CHW 5000      /* chunk width: 5000 nodes * 256B = 1.28MB window */
#define NE2 (N_NODES * NCH) /* buckets: (node, chunk), node-major contiguous */

typedef unsigned short ushort_t;
typedef unsigned int uint_t;
typedef __attribute__((ext_vector_type(8))) short bf16x8;
typedef __attribute__((ext_vector_type(4))) float f32x4;

__device__ __forceinline__ float bf2f(ushort_t u) {
    return __uint_as_float(((uint_t)u) << 16);
}
__device__ __forceinline__ ushort_t f2bf(float f) {
    uint_t b = __float_as_uint(f);
    b += 0x7FFFu + ((b >> 16) & 1u); // RNE
    return (ushort_t)(b >> 16);
}
// fp16 pair packing for CSR entry weights (low = S-channel, high = D-channel)
__device__ __forceinline__ uint_t packw(float a, float b) {
    return ((uint_t)__half_as_ushort(__float2half(b)) << 16) |
           (uint_t)__half_as_ushort(__float2half(a));
}
__device__ __forceinline__ float unpl(uint_t w) {
    return __half2float(__ushort_as_half((ushort_t)(w & 0xffffu)));
}
__device__ __forceinline__ float unph(uint_t w) {
    return __half2float(__ushort_as_half((ushort_t)(w >> 16)));
}

// ---------------- static device scratch (module BSS; d_ws untouched) ----------------
// NOTE: only reference these from device code (host sees shadow addresses - r4 fault).

__device__ int g_est;  // edge-index word stride: 1 = int32, 2 = int64
__device__ int g_is16; // 1 = float tensors bf16-packed, 0 = fp32
__device__ __align__(8) float2 g_dis2[N_NODES]; // (dis_s, dis_r)
__device__ int g_cnt2[NE2];
__device__ int g_offs2[NE2 + 1];
__device__ uint_t g_rank[N_EDGES]; // low16 = fwd rank, high16 = rev rank
__device__ int g_bsum[512];
__device__ __align__(16) uint4 g_estage[N_EDGES]; // {s, r, c2 bits, s2 bits} staged by edge_cnt
__device__ __align__(16) uint2 g_csr8[CSR_E]; // {src, half2 w}: raw (out,in) -> final (wS',wD') src-folded
__device__ __align__(16) ushort_t g_h1[(size_t)N_NODES * 128];  // bf16
__device__ __align__(16) ushort_t g_xcvt[(size_t)N_NODES * 128]; // bf16 (fp32-input fallback)
__device__ __align__(16) ushort_t g_bp1[8 * 128 * 32]; // B packed [kb][n][kk] bf16
__device__ __align__(16) ushort_t g_bp2[8 * 128 * 32];
__device__ __align__(16) ushort_t g_bp3[4 * 64 * 32];
__device__ float g_bc1[128];
__device__ float g_bc2[128];
__device__ float g_bro[64];

// ---------------- merged init: detect + cnt init + fp32->bf16 convert ----------------

__global__ __launch_bounds__(256) void init_all(const uint_t* __restrict__ xw,
                                                const int* __restrict__ eidx,
                                                const float* __restrict__ x32) {
    __shared__ int s_flags;
    if (threadIdx.x < 64) {
        uint_t w = xw[threadIdx.x];
        int elo = (w >> 7) & 0xFF;
        unsigned long long mb = __ballot(elo >= 100 && elo <= 150);
        unsigned long long me = __ballot(eidx[2 * threadIdx.x + 1] != 0);
        if (threadIdx.x == 0) {
            int is16 = (__popcll(mb) >= 48) ? 1 : 0;
            int est = me ? 1 : 2;
            s_flags = is16 | (est << 1);
        }
    }
    __syncthreads();
    int is16 = s_flags & 1;
    int t = blockIdx.x * 256 + threadIdx.x;
    if (t == 0) {
        g_is16 = is16;
        g_est = s_flags >> 1;
    }
    if (t < N_NODES) {
        int sc = t / CHW;
#pragma unroll
        for (int c = 0; c < NCH; c++) g_cnt2[t * NCH + c] = (c == sc) ? 1 : 0; // self-loop slot
    }
    if (!is16 && t < N_NODES * 128 / 8) {
        const float4* p = (const float4*)(x32 + t * 8);
        float4 a = p[0], b = p[1];
        ushort4 o0, o1;
        o0.x = f2bf(a.x); o0.y = f2bf(a.y); o0.z = f2bf(a.z); o0.w = f2bf(a.w);
        o1.x = f2bf(b.x); o1.y = f2bf(b.y); o1.z = f2bf(b.z); o1.w = f2bf(b.w);
        *(ushort4*)(g_xcvt + t * 8) = o0;
        *(ushort4*)(g_xcvt + t * 8 + 4) = o1;
    }
}

// ---------------- edge pass: ranks + staged (s,r,c2,s2). NO degree atomics ----------------
// (r1 post-mortem: 4 scattered f32 atomics/edge cost +85us and 82MB of HBM
// write-back; degrees via contiguous CSR read in deg_pass are ~10us total.)

__global__ __launch_bounds__(256) void edge_cnt(const int* __restrict__ eidx,
                                                const ushort_t* __restrict__ th16,
                                                const float* __restrict__ th32) {
    int e = blockIdx.x * 256 + threadIdx.x;
    if (e >= N_EDGES) return;
    int st = g_est;
    int s = eidx[(size_t)e * st];
    int r = eidx[((size_t)N_EDGES + e) * st];
    float t = g_is16 ? bf2f(th16[e]) : th32[e];
    float sn, cs_;
    sincosf(t, &sn, &cs_);
    float c2 = cs_ * cs_;
    float s2 = sn * sn;
    g_estage[e] = make_uint4((uint_t)s, (uint_t)r, __float_as_uint(c2), __float_as_uint(s2));
    int rf = atomicAdd(&g_cnt2[r * NCH + s / CHW], 1); // fwd: dst=r, chunk of s
    int rr = atomicAdd(&g_cnt2[s * NCH + r / CHW], 1); // rev: dst=s, chunk of r
    g_rank[e] = (uint_t)rf | ((uint_t)rr << 16);       // ranks < 65536 (max degree ~100)
}

// ---------------- scan phase 1: per-block inclusive scans ----------------

__global__ __launch_bounds__(1024) void scan1() {
    __shared__ int sd[1024];
    int i = blockIdx.x * 1024 + threadIdx.x;
    int v = (i < NE2) ? g_cnt2[i] : 0;
    sd[threadIdx.x] = v;
    __syncthreads();
    for (int o = 1; o < 1024; o <<= 1) {
        int tv = (threadIdx.x >= o) ? sd[threadIdx.x - o] : 0;
        __syncthreads();
        sd[threadIdx.x] += tv;
        __syncthreads();
    }
    if (i < NE2) g_offs2[i] = sd[threadIdx.x] - v;
    if (threadIdx.x == 1023) g_bsum[blockIdx.x] = sd[1023];
}

// ---------------- scan phase 2+3 merged: each block sums its bsum-prefix itself ----------------

__global__ __launch_bounds__(256) void scan23() {
    __shared__ int sd[256];
    int b = blockIdx.x;
    int acc = 0;
    for (int j = (int)threadIdx.x; j < b; j += 256) acc += g_bsum[j];
    sd[threadIdx.x] = acc;
    __syncthreads();
#pragma unroll
    for (int o = 128; o > 0; o >>= 1) {
        if ((int)threadIdx.x < o) sd[threadIdx.x] += sd[threadIdx.x + o];
        __syncthreads();
    }
    int base = sd[0];
    int i0 = b << 10;
#pragma unroll
    for (int u = 0; u < 4; u++) {
        int i = i0 + u * 256 + threadIdx.x;
        if (i < NE2) g_offs2[i] += base;
    }
    if (b == 0 && threadIdx.x == 0) g_offs2[NE2] = CSR_E; // sentinel
}

// ---------------- CSR fill from staged edges: ZERO atomics, raw weights ----------------

__global__ __launch_bounds__(256) void fill_all() {
    int e = blockIdx.x * 256 + threadIdx.x;
    if (e < N_EDGES) {
        uint4 stg = g_estage[e];
        int s = (int)stg.x;
        int r = (int)stg.y;
        float c2 = __uint_as_float(stg.z);
        float s2 = __uint_as_float(stg.w);
        uint_t rk = g_rank[e];
        int pf = g_offs2[r * NCH + s / CHW] + (int)(rk & 0xffffu);
        int pr = g_offs2[s * NCH + r / CHW] + (int)(rk >> 16);
        g_csr8[pf] = make_uint2((uint_t)s, packw(c2, s2)); // fwd: cs=s, out=c2, in=s2
        g_csr8[pr] = make_uint2((uint_t)r, packw(s2, c2)); // rev: cs=r, out=s2, in=c2
    }
    if (e < N_NODES) { // self-loop at rank 0 of its bucket
        g_csr8[g_offs2[e * NCH + e / CHW]] = make_uint2((uint_t)e, packw(1.0f, 1.0f));
    }
}

// ---------------- degrees (atomic-free; contiguous per-node range) ----------------

__global__ __launch_bounds__(256) void deg_pass() {
    int n = blockIdx.x * 256 + threadIdx.x;
    if (n >= N_NODES) return;
    int kb = g_offs2[n * NCH];
    int ke = g_offs2[n * NCH + NCH];
    float ds = 0.f, dr = 0.f;
    for (int k = kb; k < ke; k++) {
        uint_t w = g_csr8[k].y;
        ds += unph(w); // in_w
        dr += unpl(w); // out_w
    }
    g_dis2[n] = make_float2(rsqrtf(ds + 1e-12f), rsqrtf(dr + 1e-12f));
}

// ---------------- finalize: fold SRC factors only (dst folded in agg epilogue) ----------------

__global__ __launch_bounds__(256) void finalize_w() {
    int i = blockIdx.x * 256 + threadIdx.x;
    if (i >= CSR_E) return;
    uint2 e = g_csr8[i];
    float2 d = g_dis2[e.x]; // (dis_s, dis_r) of src
    ((uint_t*)g_csr8)[2 * (size_t)i + 1] = packw(d.x * unpl(e.y), d.y * unph(e.y));
}

// ---------------- weight prep (merged): Bp[kb][n][kk] bf16 + biases ----------------

__global__ __launch_bounds__(256) void prep_all(const ushort_t* W1s16, const float* W1s32,
                                                const ushort_t* W1d16, const float* W1d32,
                                                const ushort_t* b1s16, const float* b1s32,
                                                const ushort_t* b1d16, const float* b1d32,
                                                const ushort_t* W2s16, const float* W2s32,
                                                const ushort_t* W2d16, const float* W2d32,
                                                const ushort_t* b2s16, const float* b2s32,
                                                const ushort_t* b2d16, const float* b2d32,
                                                const ushort_t* Wro16, const float* Wro32,
                                                const ushort_t* bro16, const float* bro32) {
    int is16 = g_is16;
    int t = blockIdx.x * 256 + threadIdx.x;
    if (t < 2 * 32768) { // hidden layers
        int layer = t >> 15;
        int i = t & 32767;
        const ushort_t* Ws16 = layer ? W2s16 : W1s16;
        const float* Ws32 = layer ? W2s32 : W1s32;
        const ushort_t* Wd16 = layer ? W2d16 : W1d16;
        const float* Wd32 = layer ? W2d32 : W1d32;
        ushort_t* Bp = layer ? g_bp2 : g_bp1;
        int k = i >> 7, n = i & 127;
        ushort_t v;
        if (k < 128) {
            int idx = k * 128 + n;
            v = is16 ? Ws16[idx] : f2bf(Ws32[idx]);
        } else {
            int idx = (k - 128) * 128 + n;
            v = is16 ? Wd16[idx] : f2bf(Wd32[idx]);
        }
        int kb = k >> 5, kk = k & 31;
        Bp[((kb * 128 + n) << 5) + kk] = v;
        if (i < 128) {
            const ushort_t* bs16 = layer ? b2s16 : b1s16;
            const float* bs32 = layer ? b2s32 : b1s32;
            const ushort_t* bd16 = layer ? b2d16 : b1d16;
            const float* bd32 = layer ? b2d32 : b1d32;
            float a = is16 ? bf2f(bs16[i]) : bs32[i];
            float b = is16 ? bf2f(bd16[i]) : bd32[i];
            (layer ? g_bc2 : g_bc1)[i] = 0.5f * (a + b);
        }
    } else if (t < 2 * 32768 + 8192) { // readout
        int i = t - 2 * 32768;
        int k = i >> 6, n = i & 63;
        ushort_t v = is16 ? Wro16[i] : f2bf(Wro32[i]);
        int kb = k >> 5, kk = k & 31;
        g_bp3[((kb * 64 + n) << 5) + kk] = v;
        if (i < 64) g_bro[i] = is16 ? bf2f(bro16[i]) : bro32[i];
    }
}

// ---------------- FUSED layer: staged-broadcast gather -> LDS tile -> MFMA GEMM ----------------
// Block = 256 threads = 16 nodes (grid 3125, exact). r2 post-mortem: gather was
// latency-bound (54us @ 26% HBM, 30% VALU): 2-hop chain entry->row with 2 chains
// in flight and 16x-redundant entry loads. New scheme: lane r of each 16-lane
// group PREFETCHES entry k+16+r (16 distinct entries per load instr), the group
// processes entries k..k+15 from registers via __shfl broadcast -> row-gather
// addresses come from registers, 16 independent row loads per step. FMA order
// per feature is unchanged (ascending k) -> bit-identical to r2.
// Phase B: 4 waves x 32 output cols, KB=8 x NT=2 MFMA on the swizzled LDS tile.
// LAYER 0 stores relu(..) to g_h1; LAYER 1 keeps h2 in LDS and runs readout too.

template <int LAYER>
__global__ __launch_bounds__(256) void fused_layer(const ushort_t* __restrict__ xext,
                                                   void* __restrict__ outp) {
    __shared__ ushort_t tA[16 * 256];                       // agg tile, swizzled
    __shared__ ushort_t tH[(LAYER == 1) ? 16 * 128 : 1];    // h2 tile (L1 only)
    int w = threadIdx.x >> 6;
    int lane = threadIdx.x & 63;
    int gsel = lane >> 4; // which of the wave's 4 nodes
    int r = lane & 15;    // feature sub-block: feats 8r..8r+7
    int lrow = w * 4 + gsel;            // local row 0..15
    int node = blockIdx.x * 16 + lrow;  // exact: 3125*16 = 50000
    const ushort_t* xin = (LAYER == 0) ? (g_is16 ? xext : g_xcvt) : g_h1;

    int ks = g_offs2[node * NCH];
    int ke = g_offs2[node * NCH + NCH];
    int c0 = ke - ks;
    int cmax = c0;
    cmax = max(cmax, __shfl_xor(cmax, 16));
    cmax = max(cmax, __shfl_xor(cmax, 32));

    float accS[8], accD[8];
#pragma unroll
    for (int f = 0; f < 8; f++) { accS[f] = 0.f; accD[f] = 0.f; }

    // lane r holds entry (k + r) of its group's list (clamped; weight zeroed past c0)
    uint2 ecur = g_csr8[ks + min(r, c0 - 1)];
    int lbase = lane & 48; // group base within wave
    for (int k = 0; k < cmax; k += 16) {
        uint2 enext = ecur;
        if (k + 16 < cmax) enext = g_csr8[ks + min(k + 16 + r, c0 - 1)];
        int jend = cmax - k; // wave-uniform
#pragma unroll
        for (int j = 0; j < 16; j++) {
            if (j >= jend) break;
            uint_t ex = (uint_t)__shfl((int)ecur.x, lbase | j, 64);
            uint_t ey = (uint_t)__shfl((int)ecur.y, lbase | j, 64);
            bf16x8 v = *(const bf16x8*)(xin + (size_t)ex * 128 + r * 8);
            bool val = (k + j) < c0;
            float ws_ = val ? unpl(ey) : 0.f;
            float wd_ = val ? unph(ey) : 0.f;
#pragma unroll
            for (int f = 0; f < 8; f++) {
                float xv = bf2f((ushort_t)v[f]);
                accS[f] = fmaf(ws_, xv, accS[f]);
                accD[f] = fmaf(wd_, xv, accD[f]);
            }
        }
        ecur = enext;
    }

    float2 dn = g_dis2[node];
    float fs = 0.5f * dn.y; // S channel: 0.5 * dis_r[dst]
    float fd = 0.5f * dn.x; // D channel: 0.5 * dis_s[dst]
    uint_t oS[4], oD[4];
#pragma unroll
    for (int p = 0; p < 4; p++) {
        oS[p] = ((uint_t)f2bf(accS[2 * p + 1] * fs) << 16) | (uint_t)f2bf(accS[2 * p] * fs);
        oD[p] = ((uint_t)f2bf(accD[2 * p + 1] * fd) << 16) | (uint_t)f2bf(accD[2 * p] * fd);
    }
    int swA = (lrow & 7) << 4;
    *(uint4*)((char*)tA + ((lrow * 512 + r * 16) ^ swA)) = make_uint4(oS[0], oS[1], oS[2], oS[3]);
    *(uint4*)((char*)tA + ((lrow * 512 + 256 + r * 16) ^ swA)) = make_uint4(oD[0], oD[1], oD[2], oD[3]);
    __syncthreads();

    // ---- phase B: GEMM on the 16-row tile; wave w owns cols w*32..w*32+31 ----
    int cc = lane & 15;
    int q = lane >> 4;
    int csw = (cc & 7) << 4;
    const ushort_t* Bp = (LAYER == 0) ? g_bp1 : g_bp2;
    const float* bias = (LAYER == 0) ? g_bc1 : g_bc2;
    f32x4 acc0 = {0.f, 0.f, 0.f, 0.f};
    f32x4 acc1 = {0.f, 0.f, 0.f, 0.f};
#pragma unroll
    for (int kb = 0; kb < 8; kb++) {
        bf16x8 a = *(const bf16x8*)((const char*)tA + ((cc * 512 + kb * 64 + q * 16) ^ csw));
        bf16x8 b0 = *(const bf16x8*)(Bp + (((kb * 128 + w * 32 + cc) << 5) + q * 8));
        bf16x8 b1 = *(const bf16x8*)(Bp + (((kb * 128 + w * 32 + 16 + cc) << 5) + q * 8));
        acc0 = __builtin_amdgcn_mfma_f32_16x16x32_bf16(a, b0, acc0, 0, 0, 0);
        acc1 = __builtin_amdgcn_mfma_f32_16x16x32_bf16(a, b1, acc1, 0, 0, 0);
    }
    int mb = blockIdx.x * 16;
    float bi0 = bias[w * 32 + cc];
    float bi1 = bias[w * 32 + 16 + cc];
    if (LAYER == 0) {
#pragma unroll
        for (int rr = 0; rr < 4; rr++) {
            int m = mb + q * 4 + rr;
            g_h1[(size_t)m * 128 + w * 32 + cc] = f2bf(fmaxf(acc0[rr] + bi0, 0.f));
            g_h1[(size_t)m * 128 + w * 32 + 16 + cc] = f2bf(fmaxf(acc1[rr] + bi1, 0.f));
        }
    } else {
#pragma unroll
        for (int rr = 0; rr < 4; rr++) {
            int ml = q * 4 + rr;
            int msw = (ml & 7) << 4;
            *(ushort_t*)((char*)tH + ((ml * 256 + (w * 32 + cc) * 2) ^ msw)) =
                f2bf(fmaxf(acc0[rr] + bi0, 0.f));
            *(ushort_t*)((char*)tH + ((ml * 256 + (w * 32 + 16 + cc) * 2) ^ msw)) =
                f2bf(fmaxf(acc1[rr] + bi1, 0.f));
        }
        __syncthreads();
        // ---- phase C: readout GEMM, K=128, N=64; wave w owns cols w*16..w*16+15 ----
        f32x4 a3 = {0.f, 0.f, 0.f, 0.f};
#pragma unroll
        for (int kb = 0; kb < 4; kb++) {
            bf16x8 a = *(const bf16x8*)((const char*)tH + ((cc * 256 + kb * 64 + q * 16) ^ csw));
            bf16x8 b = *(const bf16x8*)(g_bp3 + (((kb * 64 + w * 16 + cc) << 5) + q * 8));
            a3 = __builtin_amdgcn_mfma_f32_16x16x32_bf16(a, b, a3, 0, 0, 0);
        }
        int is16 = g_is16;
        float bi = g_bro[w * 16 + cc];
#pragma unroll
        for (int rr = 0; rr < 4; rr++) {
            int m = mb + q * 4 + rr;
            float v = a3[rr] + bi;
            if (is16)
                ((ushort_t*)outp)[(size_t)m * 64 + w * 16 + cc] = f2bf(v);
            else
                ((float*)outp)[(size_t)m * 64 + w * 16 + cc] = v;
        }
    }
}

// ---------------- launch ----------------

static inline int cdiv(int a, int b) { return (a + b - 1) / b; }

extern "C" void kernel_launch(void* const* d_in, const int* in_sizes, int n_in,
                              void* d_out, int out_size, void* d_ws, size_t ws_size,
                              hipStream_t stream) {
    const void* x = d_in[0]; // [50000][128]
    const int* eidx = (const int*)d_in[1];
    const void* theta = d_in[2];
    const void* W1s = d_in[3];
    const void* W1d = d_in[4];
    const void* b1s = d_in[5];
    const void* b1d = d_in[6];
    const void* W2s = d_in[7];
    const void* W2d = d_in[8];
    const void* b2s = d_in[9];
    const void* b2d = d_in[10];
    const void* Wro = d_in[11];
    const void* bro = d_in[12];
    (void)in_sizes; (void)n_in; (void)out_size; (void)d_ws; (void)ws_size;

    const int NB2 = cdiv(NE2, 1024); // 489

    init_all<<<cdiv(N_NODES * 128 / 8, 256), 256, 0, stream>>>(
        (const uint_t*)x, eidx, (const float*)x);
    edge_cnt<<<cdiv(N_EDGES, 256), 256, 0, stream>>>(
        eidx, (const ushort_t*)theta, (const float*)theta);
    scan1<<<NB2, 1024, 0, stream>>>();
    scan23<<<NB2, 256, 0, stream>>>();
    fill_all<<<cdiv(N_EDGES, 256), 256, 0, stream>>>();
    deg_pass<<<cdiv(N_NODES, 256), 256, 0, stream>>>();
    finalize_w<<<cdiv(CSR_E, 256), 256, 0, stream>>>();
    prep_all<<<cdiv(2 * 32768 + 8192, 256), 256, 0, stream>>>(
        (const ushort_t*)W1s, (const float*)W1s, (const ushort_t*)W1d, (const float*)W1d,
        (const ushort_t*)b1s, (const float*)b1s, (const ushort_t*)b1d, (const float*)b1d,
        (const ushort_t*)W2s, (const float*)W2s, (const ushort_t*)W2d, (const float*)W2d,
        (const ushort_t*)b2s, (const float*)b2s, (const ushort_t*)b2d, (const float*)b2d,
        (const ushort_t*)Wro, (const float*)Wro, (const ushort_t*)bro, (const float*)bro);

    const int AB = N_NODES / 16; // 3125 blocks, 16 nodes each (exact)
    fused_layer<0><<<AB, 256, 0, stream>>>((const ushort_t*)x, nullptr);
    fused_layer<1><<<AB, 256, 0, stream>>>(nullptr, d_out);
}

// Round 5
// 269.677 us; speedup vs baseline: 1.4017x; 1.0089x over previous
//
#include <hip/hip_runtime.h>
#include <hip/hip_fp16.h>

#define N_NODES 50000
#define N_EDGES 400000
#define CSR_E (2 * N_EDGES + N_NODES) /* 850000 */
#define NCH 10        /* source chunks */
#define CHW 5000      /* chunk width: 5000 nodes * 256B = 1.28MB window */
#define NE2 (N_NODES * NCH) /* buckets: (node, chunk), node-major contiguous */

typedef unsigned short ushort_t;
typedef unsigned int uint_t;
typedef __attribute__((ext_vector_type(8))) short bf16x8;
typedef __attribute__((ext_vector_type(4))) float f32x4;

__device__ __forceinline__ float bf2f(ushort_t u) {
    return __uint_as_float(((uint_t)u) << 16);
}
__device__ __forceinline__ ushort_t f2bf(float f) {
    uint_t b = __float_as_uint(f);
    b += 0x7FFFu + ((b >> 16) & 1u); // RNE
    return (ushort_t)(b >> 16);
}
// fp16 pair packing for CSR entry weights (low = S-channel, high = D-channel)
__device__ __forceinline__ uint_t packw(float a, float b) {
    return ((uint_t)__half_as_ushort(__float2half(b)) << 16) |
           (uint_t)__half_as_ushort(__float2half(a));
}
__device__ __forceinline__ float unpl(uint_t w) {
    return __half2float(__ushort_as_half((ushort_t)(w & 0xffffu)));
}
__device__ __forceinline__ float unph(uint_t w) {
    return __half2float(__ushort_as_half((ushort_t)(w >> 16)));
}

// ---------------- static device scratch (module BSS; d_ws untouched) ----------------
// NOTE: only reference these from device code (host sees shadow addresses - r4 fault).

__device__ int g_est;  // edge-index word stride: 1 = int32, 2 = int64
__device__ int g_is16; // 1 = float tensors bf16-packed, 0 = fp32
__device__ __align__(8) float2 g_dis2[N_NODES]; // (dis_s, dis_r)
__device__ int g_cnt2[NE2];
__device__ int g_offs2[NE2 + 1];
__device__ uint_t g_rank[N_EDGES]; // low16 = fwd rank, high16 = rev rank
__device__ int g_bsum[512];
__device__ __align__(16) uint4 g_estage[N_EDGES]; // {s, r, c2 bits, s2 bits} staged by edge_cnt
__device__ __align__(16) uint2 g_csr8[CSR_E]; // {src, half2 w}: raw (out,in) -> final (wS',wD') src-folded
__device__ __align__(16) ushort_t g_h1[(size_t)N_NODES * 128];  // bf16
__device__ __align__(16) ushort_t g_xcvt[(size_t)N_NODES * 128]; // bf16 (fp32-input fallback)
__device__ __align__(16) ushort_t g_bp1[8 * 128 * 32]; // B packed [kb][n][kk] bf16
__device__ __align__(16) ushort_t g_bp2[8 * 128 * 32];
__device__ __align__(16) ushort_t g_bp3[4 * 64 * 32];
__device__ float g_bc1[128];
__device__ float g_bc2[128];
__device__ float g_bro[64];

// ---------------- merged init: detect + cnt init + fp32->bf16 convert ----------------

__global__ __launch_bounds__(256) void init_all(const uint_t* __restrict__ xw,
                                                const int* __restrict__ eidx,
                                                const float* __restrict__ x32) {
    __shared__ int s_flags;
    if (threadIdx.x < 64) {
        uint_t w = xw[threadIdx.x];
        int elo = (w >> 7) & 0xFF;
        unsigned long long mb = __ballot(elo >= 100 && elo <= 150);
        unsigned long long me = __ballot(eidx[2 * threadIdx.x + 1] != 0);
        if (threadIdx.x == 0) {
            int is16 = (__popcll(mb) >= 48) ? 1 : 0;
            int est = me ? 1 : 2;
            s_flags = is16 | (est << 1);
        }
    }
    __syncthreads();
    int is16 = s_flags & 1;
    int t = blockIdx.x * 256 + threadIdx.x;
    if (t == 0) {
        g_is16 = is16;
        g_est = s_flags >> 1;
    }
    if (t < N_NODES) {
        int sc = t / CHW;
#pragma unroll
        for (int c = 0; c < NCH; c++) g_cnt2[t * NCH + c] = (c == sc) ? 1 : 0; // self-loop slot
    }
    if (!is16 && t < N_NODES * 128 / 8) {
        const float4* p = (const float4*)(x32 + t * 8);
        float4 a = p[0], b = p[1];
        ushort4 o0, o1;
        o0.x = f2bf(a.x); o0.y = f2bf(a.y); o0.z = f2bf(a.z); o0.w = f2bf(a.w);
        o1.x = f2bf(b.x); o1.y = f2bf(b.y); o1.z = f2bf(b.z); o1.w = f2bf(b.w);
        *(ushort4*)(g_xcvt + t * 8) = o0;
        *(ushort4*)(g_xcvt + t * 8 + 4) = o1;
    }
}

// ---------------- edge pass: ranks + staged (s,r,c2,s2). NO degree atomics ----------------

__global__ __launch_bounds__(256) void edge_cnt(const int* __restrict__ eidx,
                                                const ushort_t* __restrict__ th16,
                                                const float* __restrict__ th32) {
    int e = blockIdx.x * 256 + threadIdx.x;
    if (e >= N_EDGES) return;
    int st = g_est;
    int s = eidx[(size_t)e * st];
    int r = eidx[((size_t)N_EDGES + e) * st];
    float t = g_is16 ? bf2f(th16[e]) : th32[e];
    float sn, cs_;
    sincosf(t, &sn, &cs_);
    float c2 = cs_ * cs_;
    float s2 = sn * sn;
    g_estage[e] = make_uint4((uint_t)s, (uint_t)r, __float_as_uint(c2), __float_as_uint(s2));
    int rf = atomicAdd(&g_cnt2[r * NCH + s / CHW], 1); // fwd: dst=r, chunk of s
    int rr = atomicAdd(&g_cnt2[s * NCH + r / CHW], 1); // rev: dst=s, chunk of r
    g_rank[e] = (uint_t)rf | ((uint_t)rr << 16);       // ranks < 65536 (max degree ~100)
}

// ---------------- scan phase 1: per-block inclusive scans ----------------

__global__ __launch_bounds__(1024) void scan1() {
    __shared__ int sd[1024];
    int i = blockIdx.x * 1024 + threadIdx.x;
    int v = (i < NE2) ? g_cnt2[i] : 0;
    sd[threadIdx.x] = v;
    __syncthreads();
    for (int o = 1; o < 1024; o <<= 1) {
        int tv = (threadIdx.x >= o) ? sd[threadIdx.x - o] : 0;
        __syncthreads();
        sd[threadIdx.x] += tv;
        __syncthreads();
    }
    if (i < NE2) g_offs2[i] = sd[threadIdx.x] - v;
    if (threadIdx.x == 1023) g_bsum[blockIdx.x] = sd[1023];
}

// ---------------- scan phase 2+3 merged: each block sums its bsum-prefix itself ----------------

__global__ __launch_bounds__(256) void scan23() {
    __shared__ int sd[256];
    int b = blockIdx.x;
    int acc = 0;
    for (int j = (int)threadIdx.x; j < b; j += 256) acc += g_bsum[j];
    sd[threadIdx.x] = acc;
    __syncthreads();
#pragma unroll
    for (int o = 128; o > 0; o >>= 1) {
        if ((int)threadIdx.x < o) sd[threadIdx.x] += sd[threadIdx.x + o];
        __syncthreads();
    }
    int base = sd[0];
    int i0 = b << 10;
#pragma unroll
    for (int u = 0; u < 4; u++) {
        int i = i0 + u * 256 + threadIdx.x;
        if (i < NE2) g_offs2[i] += base;
    }
    if (b == 0 && threadIdx.x == 0) g_offs2[NE2] = CSR_E; // sentinel
}

// ---------------- CSR fill from staged edges: ZERO atomics, raw weights ----------------

__global__ __launch_bounds__(256) void fill_all() {
    int e = blockIdx.x * 256 + threadIdx.x;
    if (e < N_EDGES) {
        uint4 stg = g_estage[e];
        int s = (int)stg.x;
        int r = (int)stg.y;
        float c2 = __uint_as_float(stg.z);
        float s2 = __uint_as_float(stg.w);
        uint_t rk = g_rank[e];
        int pf = g_offs2[r * NCH + s / CHW] + (int)(rk & 0xffffu);
        int pr = g_offs2[s * NCH + r / CHW] + (int)(rk >> 16);
        g_csr8[pf] = make_uint2((uint_t)s, packw(c2, s2)); // fwd: cs=s, out=c2, in=s2
        g_csr8[pr] = make_uint2((uint_t)r, packw(s2, c2)); // rev: cs=r, out=s2, in=c2
    }
    if (e < N_NODES) { // self-loop at rank 0 of its bucket
        g_csr8[g_offs2[e * NCH + e / CHW]] = make_uint2((uint_t)e, packw(1.0f, 1.0f));
    }
}

// ---------------- degrees (atomic-free; contiguous per-node range) ----------------

__global__ __launch_bounds__(256) void deg_pass() {
    int n = blockIdx.x * 256 + threadIdx.x;
    if (n >= N_NODES) return;
    int kb = g_offs2[n * NCH];
    int ke = g_offs2[n * NCH + NCH];
    float ds = 0.f, dr = 0.f;
    for (int k = kb; k < ke; k++) {
        uint_t w = g_csr8[k].y;
        ds += unph(w); // in_w
        dr += unpl(w); // out_w
    }
    g_dis2[n] = make_float2(rsqrtf(ds + 1e-12f), rsqrtf(dr + 1e-12f));
}

// ---------------- finalize: fold SRC factors only (dst folded in agg epilogue) ----------------

__global__ __launch_bounds__(256) void finalize_w() {
    int i = blockIdx.x * 256 + threadIdx.x;
    if (i >= CSR_E) return;
    uint2 e = g_csr8[i];
    float2 d = g_dis2[e.x]; // (dis_s, dis_r) of src
    ((uint_t*)g_csr8)[2 * (size_t)i + 1] = packw(d.x * unpl(e.y), d.y * unph(e.y));
}

// ---------------- weight prep (merged): Bp[kb][n][kk] bf16 + biases ----------------

__global__ __launch_bounds__(256) void prep_all(const ushort_t* W1s16, const float* W1s32,
                                                const ushort_t* W1d16, const float* W1d32,
                                                const ushort_t* b1s16, const float* b1s32,
                                                const ushort_t* b1d16, const float* b1d32,
                                                const ushort_t* W2s16, const float* W2s32,
                                                const ushort_t* W2d16, const float* W2d32,
                                                const ushort_t* b2s16, const float* b2s32,
                                                const ushort_t* b2d16, const float* b2d32,
                                                const ushort_t* Wro16, const float* Wro32,
                                                const ushort_t* bro16, const float* bro32) {
    int is16 = g_is16;
    int t = blockIdx.x * 256 + threadIdx.x;
    if (t < 2 * 32768) { // hidden layers
        int layer = t >> 15;
        int i = t & 32767;
        const ushort_t* Ws16 = layer ? W2s16 : W1s16;
        const float* Ws32 = layer ? W2s32 : W1s32;
        const ushort_t* Wd16 = layer ? W2d16 : W1d16;
        const float* Wd32 = layer ? W2d32 : W1d32;
        ushort_t* Bp = layer ? g_bp2 : g_bp1;
        int k = i >> 7, n = i & 127;
        ushort_t v;
        if (k < 128) {
            int idx = k * 128 + n;
            v = is16 ? Ws16[idx] : f2bf(Ws32[idx]);
        } else {
            int idx = (k - 128) * 128 + n;
            v = is16 ? Wd16[idx] : f2bf(Wd32[idx]);
        }
        int kb = k >> 5, kk = k & 31;
        Bp[((kb * 128 + n) << 5) + kk] = v;
        if (i < 128) {
            const ushort_t* bs16 = layer ? b2s16 : b1s16;
            const float* bs32 = layer ? b2s32 : b1s32;
            const ushort_t* bd16 = layer ? b2d16 : b1d16;
            const float* bd32 = layer ? b2d32 : b1d32;
            float a = is16 ? bf2f(bs16[i]) : bs32[i];
            float b = is16 ? bf2f(bd16[i]) : bd32[i];
            (layer ? g_bc2 : g_bc1)[i] = 0.5f * (a + b);
        }
    } else if (t < 2 * 32768 + 8192) { // readout
        int i = t - 2 * 32768;
        int k = i >> 6, n = i & 63;
        ushort_t v = is16 ? Wro16[i] : f2bf(Wro32[i]);
        int kb = k >> 5, kk = k & 31;
        g_bp3[((kb * 64 + n) << 5) + kk] = v;
        if (i < 64) g_bro[i] = is16 ? bf2f(bro16[i]) : bro32[i];
    }
}

// ---------------- FUSED layer: batched-broadcast gather -> LDS tile -> MFMA GEMM ----------------
// r4 post-mortem: the per-j `break` kept the window loop a serial
// shfl->load->FMA->branch chain (2 loads in flight) -> same 54us as r2.
// Now: branch-free 16-entry windows processed as two 8-batches; all 8 shfls +
// all 8 row loads issue before any FMA consumes them -> ~8 independent row
// loads in flight per wave. Entries past c0 clamp to the last entry with
// weights zeroed -> accumulation order identical (bit-exact vs r2/r4).
// Plus bijective XCD-chunked swizzle (T1/m204; 3125 = 8*390+5) so concurrent
// blocks on one XCD are node-contiguous -> shared chunk windows in per-XCD L2.

template <int LAYER>
__global__ __launch_bounds__(256) void fused_layer(const ushort_t* __restrict__ xext,
                                                   void* __restrict__ outp) {
    __shared__ ushort_t tA[16 * 256];                       // agg tile, swizzled
    __shared__ ushort_t tH[(LAYER == 1) ? 16 * 128 : 1];    // h2 tile (L1 only)
    int w = threadIdx.x >> 6;
    int lane = threadIdx.x & 63;
    int gsel = lane >> 4; // which of the wave's 4 nodes
    int r = lane & 15;    // feature sub-block: feats 8r..8r+7
    int lrow = w * 4 + gsel;            // local row 0..15

    // bijective XCD-chunked swizzle: nwg=3125, q=390, rem=5
    int bid = blockIdx.x;
    int xcd = bid & 7;
    int idx = bid >> 3;
    int nbid = (xcd < 5 ? xcd * 391 : 5 * 391 + (xcd - 5) * 390) + idx;

    int node = nbid * 16 + lrow;        // exact: 3125*16 = 50000
    const ushort_t* xin = (LAYER == 0) ? (g_is16 ? xext : g_xcvt) : g_h1;

    int ks = g_offs2[node * NCH];
    int ke = g_offs2[node * NCH + NCH];
    int c0 = ke - ks;
    int cmax = c0;
    cmax = max(cmax, __shfl_xor(cmax, 16));
    cmax = max(cmax, __shfl_xor(cmax, 32));

    float accS[8], accD[8];
#pragma unroll
    for (int f = 0; f < 8; f++) { accS[f] = 0.f; accD[f] = 0.f; }

    // lane r holds entry (k + r) of its group's list (clamped; weight zeroed past c0)
    uint2 ecur = g_csr8[ks + min(r, c0 - 1)];
    int lbase = lane & 48; // group base within wave
    for (int k = 0; k < cmax; k += 16) {
        uint2 enext = ecur;
        if (k + 16 < cmax) enext = g_csr8[ks + min(k + 16 + r, c0 - 1)];
#pragma unroll
        for (int h = 0; h < 2; h++) { // two branch-free 8-batches
            uint_t eys[8];
            bf16x8 vs[8];
#pragma unroll
            for (int j = 0; j < 8; j++) {
                int jj = h * 8 + j;
                uint_t ex = (uint_t)__shfl((int)ecur.x, lbase | jj, 64);
                eys[j] = (uint_t)__shfl((int)ecur.y, lbase | jj, 64);
                vs[j] = *(const bf16x8*)(xin + (size_t)ex * 128 + r * 8);
            }
#pragma unroll
            for (int j = 0; j < 8; j++) {
                int jj = h * 8 + j;
                bool val = (k + jj) < c0;
                float ws_ = val ? unpl(eys[j]) : 0.f;
                float wd_ = val ? unph(eys[j]) : 0.f;
#pragma unroll
                for (int f = 0; f < 8; f++) {
                    float xv = bf2f((ushort_t)vs[j][f]);
                    accS[f] = fmaf(ws_, xv, accS[f]);
                    accD[f] = fmaf(wd_, xv, accD[f]);
                }
            }
        }
        ecur = enext;
    }

    float2 dn = g_dis2[node];
    float fs = 0.5f * dn.y; // S channel: 0.5 * dis_r[dst]
    float fd = 0.5f * dn.x; // D channel: 0.5 * dis_s[dst]
    uint_t oS[4], oD[4];
#pragma unroll
    for (int p = 0; p < 4; p++) {
        oS[p] = ((uint_t)f2bf(accS[2 * p + 1] * fs) << 16) | (uint_t)f2bf(accS[2 * p] * fs);
        oD[p] = ((uint_t)f2bf(accD[2 * p + 1] * fd) << 16) | (uint_t)f2bf(accD[2 * p] * fd);
    }
    int swA = (lrow & 7) << 4;
    *(uint4*)((char*)tA + ((lrow * 512 + r * 16) ^ swA)) = make_uint4(oS[0], oS[1], oS[2], oS[3]);
    *(uint4*)((char*)tA + ((lrow * 512 + 256 + r * 16) ^ swA)) = make_uint4(oD[0], oD[1], oD[2], oD[3]);
    __syncthreads();

    // ---- phase B: GEMM on the 16-row tile; wave w owns cols w*32..w*32+31 ----
    int cc = lane & 15;
    int q = lane >> 4;
    int csw = (cc & 7) << 4;
    const ushort_t* Bp = (LAYER == 0) ? g_bp1 : g_bp2;
    const float* bias = (LAYER == 0) ? g_bc1 : g_bc2;
    f32x4 acc0 = {0.f, 0.f, 0.f, 0.f};
    f32x4 acc1 = {0.f, 0.f, 0.f, 0.f};
#pragma unroll
    for (int kb = 0; kb < 8; kb++) {
        bf16x8 a = *(const bf16x8*)((const char*)tA + ((cc * 512 + kb * 64 + q * 16) ^ csw));
        bf16x8 b0 = *(const bf16x8*)(Bp + (((kb * 128 + w * 32 + cc) << 5) + q * 8));
        bf16x8 b1 = *(const bf16x8*)(Bp + (((kb * 128 + w * 32 + 16 + cc) << 5) + q * 8));
        acc0 = __builtin_amdgcn_mfma_f32_16x16x32_bf16(a, b0, acc0, 0, 0, 0);
        acc1 = __builtin_amdgcn_mfma_f32_16x16x32_bf16(a, b1, acc1, 0, 0, 0);
    }
    int mb = nbid * 16;
    float bi0 = bias[w * 32 + cc];
    float bi1 = bias[w * 32 + 16 + cc];
    if (LAYER == 0) {
#pragma unroll
        for (int rr = 0; rr < 4; rr++) {
            int m = mb + q * 4 + rr;
            g_h1[(size_t)m * 128 + w * 32 + cc] = f2bf(fmaxf(acc0[rr] + bi0, 0.f));
            g_h1[(size_t)m * 128 + w * 32 + 16 + cc] = f2bf(fmaxf(acc1[rr] + bi1, 0.f));
        }
    } else {
#pragma unroll
        for (int rr = 0; rr < 4; rr++) {
            int ml = q * 4 + rr;
            int msw = (ml & 7) << 4;
            *(ushort_t*)((char*)tH + ((ml * 256 + (w * 32 + cc) * 2) ^ msw)) =
                f2bf(fmaxf(acc0[rr] + bi0, 0.f));
            *(ushort_t*)((char*)tH + ((ml * 256 + (w * 32 + 16 + cc) * 2) ^ msw)) =
                f2bf(fmaxf(acc1[rr] + bi1, 0.f));
        }
        __syncthreads();
        // ---- phase C: readout GEMM, K=128, N=64; wave w owns cols w*16..w*16+15 ----
        f32x4 a3 = {0.f, 0.f, 0.f, 0.f};
#pragma unroll
        for (int kb = 0; kb < 4; kb++) {
            bf16x8 a = *(const bf16x8*)((const char*)tH + ((cc * 256 + kb * 64 + q * 16) ^ csw));
            bf16x8 b = *(const bf16x8*)(g_bp3 + (((kb * 64 + w * 16 + cc) << 5) + q * 8));
            a3 = __builtin_amdgcn_mfma_f32_16x16x32_bf16(a, b, a3, 0, 0, 0);
        }
        int is16 = g_is16;
        float bi = g_bro[w * 16 + cc];
#pragma unroll
        for (int rr = 0; rr < 4; rr++) {
            int m = mb + q * 4 + rr;
            float v = a3[rr] + bi;
            if (is16)
                ((ushort_t*)outp)[(size_t)m * 64 + w * 16 + cc] = f2bf(v);
            else
                ((float*)outp)[(size_t)m * 64 + w * 16 + cc] = v;
        }
    }
}

// ---------------- launch ----------------

static inline int cdiv(int a, int b) { return (a + b - 1) / b; }

extern "C" void kernel_launch(void* const* d_in, const int* in_sizes, int n_in,
                              void* d_out, int out_size, void* d_ws, size_t ws_size,
                              hipStream_t stream) {
    const void* x = d_in[0]; // [50000][128]
    const int* eidx = (const int*)d_in[1];
    const void* theta = d_in[2];
    const void* W1s = d_in[3];
    const void* W1d = d_in[4];
    const void* b1s = d_in[5];
    const void* b1d = d_in[6];
    const void* W2s = d_in[7];
    const void* W2d = d_in[8];
    const void* b2s = d_in[9];
    const void* b2d = d_in[10];
    const void* Wro = d_in[11];
    const void* bro = d_in[12];
    (void)in_sizes; (void)n_in; (void)out_size; (void)d_ws; (void)ws_size;

    const int NB2 = cdiv(NE2, 1024); // 489

    init_all<<<cdiv(N_NODES * 128 / 8, 256), 256, 0, stream>>>(
        (const uint_t*)x, eidx, (const float*)x);
    edge_cnt<<<cdiv(N_EDGES, 256), 256, 0, stream>>>(
        eidx, (const ushort_t*)theta, (const float*)theta);
    scan1<<<NB2, 1024, 0, stream>>>();
    scan23<<<NB2, 256, 0, stream>>>();
    fill_all<<<cdiv(N_EDGES, 256), 256, 0, stream>>>();
    deg_pass<<<cdiv(N_NODES, 256), 256, 0, stream>>>();
    finalize_w<<<cdiv(CSR_E, 256), 256, 0, stream>>>();
    prep_all<<<cdiv(2 * 32768 + 8192, 256), 256, 0, stream>>>(
        (const ushort_t*)W1s, (const float*)W1s, (const ushort_t*)W1d, (const float*)W1d,
        (const ushort_t*)b1s, (const float*)b1s, (const ushort_t*)b1d, (const float*)b1d,
        (const ushort_t*)W2s, (const float*)W2s, (const ushort_t*)W2d, (const float*)W2d,
        (const ushort_t*)b2s, (const float*)b2s, (const ushort_t*)b2d, (const float*)b2d,
        (const ushort_t*)Wro, (const float*)Wro, (const ushort_t*)bro, (const float*)bro);

    const int AB = N_NODES / 16; // 3125 blocks, 16 nodes each (exact)
    fused_layer<0><<<AB, 256, 0, stream>>>((const ushort_t*)x, nullptr);
    fused_layer<1><<<AB, 256, 0, stream>>>(nullptr, d_out);
}

// Round 6
// 258.724 us; speedup vs baseline: 1.4611x; 1.0423x over previous
//
#include <hip/hip_runtime.h>
#include <hip/hip_fp16.h>

#define N_NODES 50000
#define N_EDGES 400000
#define CSR_E (2 * N_EDGES + N_NODES) /* 850000 */
#define NCH 10        /* source chunks */
#define CHW 5000      /* chunk width: 5000 nodes * 256B = 1.28MB window */
#define NE2 (N_NODES * NCH) /* buckets: (node, chunk), node-major contiguous */

typedef unsigned short ushort_t;
typedef unsigned int uint_t;
typedef __attribute__((ext_vector_type(8))) short bf16x8;
typedef __attribute__((ext_vector_type(4))) float f32x4;

__device__ __forceinline__ float bf2f(ushort_t u) {
    return __uint_as_float(((uint_t)u) << 16);
}
__device__ __forceinline__ ushort_t f2bf(float f) {
    uint_t b = __float_as_uint(f);
    b += 0x7FFFu + ((b >> 16) & 1u); // RNE
    return (ushort_t)(b >> 16);
}
// fp16 pair packing for CSR entry weights (low = S-channel, high = D-channel)
__device__ __forceinline__ uint_t packw(float a, float b) {
    return ((uint_t)__half_as_ushort(__float2half(b)) << 16) |
           (uint_t)__half_as_ushort(__float2half(a));
}
__device__ __forceinline__ float unpl(uint_t w) {
    return __half2float(__ushort_as_half((ushort_t)(w & 0xffffu)));
}
__device__ __forceinline__ float unph(uint_t w) {
    return __half2float(__ushort_as_half((ushort_t)(w >> 16)));
}

// ---------------- static device scratch (module BSS; d_ws untouched) ----------------
// NOTE: only reference these from device code (host sees shadow addresses - r4 fault).

__device__ int g_est;  // edge-index word stride: 1 = int32, 2 = int64
__device__ int g_is16; // 1 = float tensors bf16-packed, 0 = fp32
__device__ __align__(8) float2 g_dis2[N_NODES]; // (dis_s, dis_r)
__device__ int g_cnt2[NE2];
__device__ int g_offs2[NE2 + 1];
__device__ uint_t g_rank[N_EDGES]; // low16 = fwd rank, high16 = rev rank
__device__ int g_bsum[512];
__device__ __align__(16) uint4 g_estage[N_EDGES]; // {s, r, c2 bits, s2 bits} staged by edge_cnt
__device__ __align__(16) uint2 g_csr8[CSR_E]; // {src, half2 w}: raw (out,in) -> final (wS',wD') src-folded
__device__ __align__(16) ushort_t g_h1[(size_t)N_NODES * 128];  // bf16
__device__ __align__(16) ushort_t g_xcvt[(size_t)N_NODES * 128]; // bf16 (fp32-input fallback)
__device__ __align__(16) ushort_t g_bp1[8 * 128 * 32]; // B packed [kb][n][kk] bf16
__device__ __align__(16) ushort_t g_bp2[8 * 128 * 32];
__device__ __align__(16) ushort_t g_bp3[4 * 64 * 32];
__device__ float g_bc1[128];
__device__ float g_bc2[128];
__device__ float g_bro[64];

// ---------------- merged init: detect + cnt init + fp32->bf16 convert ----------------

__global__ __launch_bounds__(256) void init_all(const uint_t* __restrict__ xw,
                                                const int* __restrict__ eidx,
                                                const float* __restrict__ x32) {
    __shared__ int s_flags;
    if (threadIdx.x < 64) {
        uint_t w = xw[threadIdx.x];
        int elo = (w >> 7) & 0xFF;
        unsigned long long mb = __ballot(elo >= 100 && elo <= 150);
        unsigned long long me = __ballot(eidx[2 * threadIdx.x + 1] != 0);
        if (threadIdx.x == 0) {
            int is16 = (__popcll(mb) >= 48) ? 1 : 0;
            int est = me ? 1 : 2;
            s_flags = is16 | (est << 1);
        }
    }
    __syncthreads();
    int is16 = s_flags & 1;
    int t = blockIdx.x * 256 + threadIdx.x;
    if (t == 0) {
        g_is16 = is16;
        g_est = s_flags >> 1;
    }
    if (t < N_NODES) {
        int sc = t / CHW;
#pragma unroll
        for (int c = 0; c < NCH; c++) g_cnt2[t * NCH + c] = (c == sc) ? 1 : 0; // self-loop slot
    }
    if (!is16 && t < N_NODES * 128 / 8) {
        const float4* p = (const float4*)(x32 + t * 8);
        float4 a = p[0], b = p[1];
        ushort4 o0, o1;
        o0.x = f2bf(a.x); o0.y = f2bf(a.y); o0.z = f2bf(a.z); o0.w = f2bf(a.w);
        o1.x = f2bf(b.x); o1.y = f2bf(b.y); o1.z = f2bf(b.z); o1.w = f2bf(b.w);
        *(ushort4*)(g_xcvt + t * 8) = o0;
        *(ushort4*)(g_xcvt + t * 8 + 4) = o1;
    }
}

// ---------------- edge pass: ranks + staged (s,r,c2,s2). NO degree atomics ----------------

__global__ __launch_bounds__(256) void edge_cnt(const int* __restrict__ eidx,
                                                const ushort_t* __restrict__ th16,
                                                const float* __restrict__ th32) {
    int e = blockIdx.x * 256 + threadIdx.x;
    if (e >= N_EDGES) return;
    int st = g_est;
    int s = eidx[(size_t)e * st];
    int r = eidx[((size_t)N_EDGES + e) * st];
    float t = g_is16 ? bf2f(th16[e]) : th32[e];
    float sn, cs_;
    sincosf(t, &sn, &cs_);
    float c2 = cs_ * cs_;
    float s2 = sn * sn;
    g_estage[e] = make_uint4((uint_t)s, (uint_t)r, __float_as_uint(c2), __float_as_uint(s2));
    int rf = atomicAdd(&g_cnt2[r * NCH + s / CHW], 1); // fwd: dst=r, chunk of s
    int rr = atomicAdd(&g_cnt2[s * NCH + r / CHW], 1); // rev: dst=s, chunk of r
    g_rank[e] = (uint_t)rf | ((uint_t)rr << 16);       // ranks < 65536 (max degree ~100)
}

// ---------------- scan phase 1: per-block inclusive scans ----------------

__global__ __launch_bounds__(1024) void scan1() {
    __shared__ int sd[1024];
    int i = blockIdx.x * 1024 + threadIdx.x;
    int v = (i < NE2) ? g_cnt2[i] : 0;
    sd[threadIdx.x] = v;
    __syncthreads();
    for (int o = 1; o < 1024; o <<= 1) {
        int tv = (threadIdx.x >= o) ? sd[threadIdx.x - o] : 0;
        __syncthreads();
        sd[threadIdx.x] += tv;
        __syncthreads();
    }
    if (i < NE2) g_offs2[i] = sd[threadIdx.x] - v;
    if (threadIdx.x == 1023) g_bsum[blockIdx.x] = sd[1023];
}

// ---------------- scan phase 2+3 merged: each block sums its bsum-prefix itself ----------------

__global__ __launch_bounds__(256) void scan23() {
    __shared__ int sd[256];
    int b = blockIdx.x;
    int acc = 0;
    for (int j = (int)threadIdx.x; j < b; j += 256) acc += g_bsum[j];
    sd[threadIdx.x] = acc;
    __syncthreads();
#pragma unroll
    for (int o = 128; o > 0; o >>= 1) {
        if ((int)threadIdx.x < o) sd[threadIdx.x] += sd[threadIdx.x + o];
        __syncthreads();
    }
    int base = sd[0];
    int i0 = b << 10;
#pragma unroll
    for (int u = 0; u < 4; u++) {
        int i = i0 + u * 256 + threadIdx.x;
        if (i < NE2) g_offs2[i] += base;
    }
    if (b == 0 && threadIdx.x == 0) g_offs2[NE2] = CSR_E; // sentinel
}

// ---------------- CSR fill from staged edges: ZERO atomics, raw weights ----------------

__global__ __launch_bounds__(256) void fill_all() {
    int e = blockIdx.x * 256 + threadIdx.x;
    if (e < N_EDGES) {
        uint4 stg = g_estage[e];
        int s = (int)stg.x;
        int r = (int)stg.y;
        float c2 = __uint_as_float(stg.z);
        float s2 = __uint_as_float(stg.w);
        uint_t rk = g_rank[e];
        int pf = g_offs2[r * NCH + s / CHW] + (int)(rk & 0xffffu);
        int pr = g_offs2[s * NCH + r / CHW] + (int)(rk >> 16);
        g_csr8[pf] = make_uint2((uint_t)s, packw(c2, s2)); // fwd: cs=s, out=c2, in=s2
        g_csr8[pr] = make_uint2((uint_t)r, packw(s2, c2)); // rev: cs=r, out=s2, in=c2
    }
    if (e < N_NODES) { // self-loop at rank 0 of its bucket
        g_csr8[g_offs2[e * NCH + e / CHW]] = make_uint2((uint_t)e, packw(1.0f, 1.0f));
    }
}

// ---------------- degrees (atomic-free; contiguous per-node range) ----------------

__global__ __launch_bounds__(256) void deg_pass() {
    int n = blockIdx.x * 256 + threadIdx.x;
    if (n >= N_NODES) return;
    int kb = g_offs2[n * NCH];
    int ke = g_offs2[n * NCH + NCH];
    float ds = 0.f, dr = 0.f;
    for (int k = kb; k < ke; k++) {
        uint_t w = g_csr8[k].y;
        ds += unph(w); // in_w
        dr += unpl(w); // out_w
    }
    g_dis2[n] = make_float2(rsqrtf(ds + 1e-12f), rsqrtf(dr + 1e-12f));
}

// ---------------- finalize: fold SRC factors only (dst folded in agg epilogue) ----------------

__global__ __launch_bounds__(256) void finalize_w() {
    int i = blockIdx.x * 256 + threadIdx.x;
    if (i >= CSR_E) return;
    uint2 e = g_csr8[i];
    float2 d = g_dis2[e.x]; // (dis_s, dis_r) of src
    ((uint_t*)g_csr8)[2 * (size_t)i + 1] = packw(d.x * unpl(e.y), d.y * unph(e.y));
}

// ---------------- weight prep (merged): Bp[kb][n][kk] bf16 + biases ----------------

__global__ __launch_bounds__(256) void prep_all(const ushort_t* W1s16, const float* W1s32,
                                                const ushort_t* W1d16, const float* W1d32,
                                                const ushort_t* b1s16, const float* b1s32,
                                                const ushort_t* b1d16, const float* b1d32,
                                                const ushort_t* W2s16, const float* W2s32,
                                                const ushort_t* W2d16, const float* W2d32,
                                                const ushort_t* b2s16, const float* b2s32,
                                                const ushort_t* b2d16, const float* b2d32,
                                                const ushort_t* Wro16, const float* Wro32,
                                                const ushort_t* bro16, const float* bro32) {
    int is16 = g_is16;
    int t = blockIdx.x * 256 + threadIdx.x;
    if (t < 2 * 32768) { // hidden layers
        int layer = t >> 15;
        int i = t & 32767;
        const ushort_t* Ws16 = layer ? W2s16 : W1s16;
        const float* Ws32 = layer ? W2s32 : W1s32;
        const ushort_t* Wd16 = layer ? W2d16 : W1d16;
        const float* Wd32 = layer ? W2d32 : W1d32;
        ushort_t* Bp = layer ? g_bp2 : g_bp1;
        int k = i >> 7, n = i & 127;
        ushort_t v;
        if (k < 128) {
            int idx = k * 128 + n;
            v = is16 ? Ws16[idx] : f2bf(Ws32[idx]);
        } else {
            int idx = (k - 128) * 128 + n;
            v = is16 ? Wd16[idx] : f2bf(Wd32[idx]);
        }
        int kb = k >> 5, kk = k & 31;
        Bp[((kb * 128 + n) << 5) + kk] = v;
        if (i < 128) {
            const ushort_t* bs16 = layer ? b2s16 : b1s16;
            const float* bs32 = layer ? b2s32 : b1s32;
            const ushort_t* bd16 = layer ? b2d16 : b1d16;
            const float* bd32 = layer ? b2d32 : b1d32;
            float a = is16 ? bf2f(bs16[i]) : bs32[i];
            float b = is16 ? bf2f(bd16[i]) : bd32[i];
            (layer ? g_bc2 : g_bc1)[i] = 0.5f * (a + b);
        }
    } else if (t < 2 * 32768 + 8192) { // readout
        int i = t - 2 * 32768;
        int k = i >> 6, n = i & 63;
        ushort_t v = is16 ? Wro16[i] : f2bf(Wro32[i]);
        int kb = k >> 5, kk = k & 31;
        g_bp3[((kb * 64 + n) << 5) + kk] = v;
        if (i < 64) g_bro[i] = is16 ? bf2f(bro16[i]) : bro32[i];
    }
}

// ---------------- FUSED layer: 4-batched broadcast gather -> LDS tile -> MFMA GEMM ----------------
// r5 post-mortem: 8-deep batches cost 40 VGPR of staging (occ 45->28%) - net loss;
// XCD swizzle RAISED FETCH 93->112MB - dropped. Now: 4-deep branch-free batches
// (vs[4]+eys[4] = 20 VGPR staging); early-exit only BETWEEN batches (wave-uniform)
// so each batch's 4 shfls + 4 independent row loads issue back-to-back. Target:
// VGPR ~60 (8 waves/SIMD eligible), MLP 4/lane vs r2's 2. Dummy entries (clamped,
// zero weight) add exact +0.0 in unchanged order -> bit-identical to r2/r4.

template <int LAYER>
__global__ __launch_bounds__(256) void fused_layer(const ushort_t* __restrict__ xext,
                                                   void* __restrict__ outp) {
    __shared__ ushort_t tA[16 * 256];                       // agg tile, swizzled
    __shared__ ushort_t tH[(LAYER == 1) ? 16 * 128 : 1];    // h2 tile (L1 only)
    int w = threadIdx.x >> 6;
    int lane = threadIdx.x & 63;
    int gsel = lane >> 4; // which of the wave's 4 nodes
    int r = lane & 15;    // feature sub-block: feats 8r..8r+7
    int lrow = w * 4 + gsel;            // local row 0..15
    int node = blockIdx.x * 16 + lrow;  // exact: 3125*16 = 50000
    const ushort_t* xin = (LAYER == 0) ? (g_is16 ? xext : g_xcvt) : g_h1;

    int ks = g_offs2[node * NCH];
    int ke = g_offs2[node * NCH + NCH];
    int c0 = ke - ks;
    int cmax = c0;
    cmax = max(cmax, __shfl_xor(cmax, 16));
    cmax = max(cmax, __shfl_xor(cmax, 32));

    float accS[8], accD[8];
#pragma unroll
    for (int f = 0; f < 8; f++) { accS[f] = 0.f; accD[f] = 0.f; }

    // lane r holds entry (k + r) of its group's list (clamped; weight zeroed past c0)
    uint2 ecur = g_csr8[ks + min(r, c0 - 1)];
    int lbase = lane & 48; // group base within wave
    for (int k = 0; k < cmax; k += 16) {
        uint2 enext = ecur;
        if (k + 16 < cmax) enext = g_csr8[ks + min(k + 16 + r, c0 - 1)];
#pragma unroll
        for (int h = 0; h < 4; h++) { // branch-free 4-batches; exit between batches
            int kh = k + h * 4;
            if (kh >= cmax) break; // wave-uniform
            uint_t eys[4];
            bf16x8 vs[4];
#pragma unroll
            for (int j = 0; j < 4; j++) {
                int jj = h * 4 + j;
                uint_t ex = (uint_t)__shfl((int)ecur.x, lbase | jj, 64);
                eys[j] = (uint_t)__shfl((int)ecur.y, lbase | jj, 64);
                vs[j] = *(const bf16x8*)(xin + (size_t)ex * 128 + r * 8);
            }
#pragma unroll
            for (int j = 0; j < 4; j++) {
                bool val = (kh + j) < c0;
                float ws_ = val ? unpl(eys[j]) : 0.f;
                float wd_ = val ? unph(eys[j]) : 0.f;
#pragma unroll
                for (int f = 0; f < 8; f++) {
                    float xv = bf2f((ushort_t)vs[j][f]);
                    accS[f] = fmaf(ws_, xv, accS[f]);
                    accD[f] = fmaf(wd_, xv, accD[f]);
                }
            }
        }
        ecur = enext;
    }

    float2 dn = g_dis2[node];
    float fs = 0.5f * dn.y; // S channel: 0.5 * dis_r[dst]
    float fd = 0.5f * dn.x; // D channel: 0.5 * dis_s[dst]
    uint_t oS[4], oD[4];
#pragma unroll
    for (int p = 0; p < 4; p++) {
        oS[p] = ((uint_t)f2bf(accS[2 * p + 1] * fs) << 16) | (uint_t)f2bf(accS[2 * p] * fs);
        oD[p] = ((uint_t)f2bf(accD[2 * p + 1] * fd) << 16) | (uint_t)f2bf(accD[2 * p] * fd);
    }
    int swA = (lrow & 7) << 4;
    *(uint4*)((char*)tA + ((lrow * 512 + r * 16) ^ swA)) = make_uint4(oS[0], oS[1], oS[2], oS[3]);
    *(uint4*)((char*)tA + ((lrow * 512 + 256 + r * 16) ^ swA)) = make_uint4(oD[0], oD[1], oD[2], oD[3]);
    __syncthreads();

    // ---- phase B: GEMM on the 16-row tile; wave w owns cols w*32..w*32+31 ----
    int cc = lane & 15;
    int q = lane >> 4;
    int csw = (cc & 7) << 4;
    const ushort_t* Bp = (LAYER == 0) ? g_bp1 : g_bp2;
    const float* bias = (LAYER == 0) ? g_bc1 : g_bc2;
    f32x4 acc0 = {0.f, 0.f, 0.f, 0.f};
    f32x4 acc1 = {0.f, 0.f, 0.f, 0.f};
#pragma unroll
    for (int kb = 0; kb < 8; kb++) {
        bf16x8 a = *(const bf16x8*)((const char*)tA + ((cc * 512 + kb * 64 + q * 16) ^ csw));
        bf16x8 b0 = *(const bf16x8*)(Bp + (((kb * 128 + w * 32 + cc) << 5) + q * 8));
        bf16x8 b1 = *(const bf16x8*)(Bp + (((kb * 128 + w * 32 + 16 + cc) << 5) + q * 8));
        acc0 = __builtin_amdgcn_mfma_f32_16x16x32_bf16(a, b0, acc0, 0, 0, 0);
        acc1 = __builtin_amdgcn_mfma_f32_16x16x32_bf16(a, b1, acc1, 0, 0, 0);
    }
    int mb = blockIdx.x * 16;
    float bi0 = bias[w * 32 + cc];
    float bi1 = bias[w * 32 + 16 + cc];
    if (LAYER == 0) {
#pragma unroll
        for (int rr = 0; rr < 4; rr++) {
            int m = mb + q * 4 + rr;
            g_h1[(size_t)m * 128 + w * 32 + cc] = f2bf(fmaxf(acc0[rr] + bi0, 0.f));
            g_h1[(size_t)m * 128 + w * 32 + 16 + cc] = f2bf(fmaxf(acc1[rr] + bi1, 0.f));
        }
    } else {
#pragma unroll
        for (int rr = 0; rr < 4; rr++) {
            int ml = q * 4 + rr;
            int msw = (ml & 7) << 4;
            *(ushort_t*)((char*)tH + ((ml * 256 + (w * 32 + cc) * 2) ^ msw)) =
                f2bf(fmaxf(acc0[rr] + bi0, 0.f));
            *(ushort_t*)((char*)tH + ((ml * 256 + (w * 32 + 16 + cc) * 2) ^ msw)) =
                f2bf(fmaxf(acc1[rr] + bi1, 0.f));
        }
        __syncthreads();
        // ---- phase C: readout GEMM, K=128, N=64; wave w owns cols w*16..w*16+15 ----
        f32x4 a3 = {0.f, 0.f, 0.f, 0.f};
#pragma unroll
        for (int kb = 0; kb < 4; kb++) {
            bf16x8 a = *(const bf16x8*)((const char*)tH + ((cc * 256 + kb * 64 + q * 16) ^ csw));
            bf16x8 b = *(const bf16x8*)(g_bp3 + (((kb * 64 + w * 16 + cc) << 5) + q * 8));
            a3 = __builtin_amdgcn_mfma_f32_16x16x32_bf16(a, b, a3, 0, 0, 0);
        }
        int is16 = g_is16;
        float bi = g_bro[w * 16 + cc];
#pragma unroll
        for (int rr = 0; rr < 4; rr++) {
            int m = mb + q * 4 + rr;
            float v = a3[rr] + bi;
            if (is16)
                ((ushort_t*)outp)[(size_t)m * 64 + w * 16 + cc] = f2bf(v);
            else
                ((float*)outp)[(size_t)m * 64 + w * 16 + cc] = v;
        }
    }
}

// ---------------- launch ----------------

static inline int cdiv(int a, int b) { return (a + b - 1) / b; }

extern "C" void kernel_launch(void* const* d_in, const int* in_sizes, int n_in,
                              void* d_out, int out_size, void* d_ws, size_t ws_size,
                              hipStream_t stream) {
    const void* x = d_in[0]; // [50000][128]
    const int* eidx = (const int*)d_in[1];
    const void* theta = d_in[2];
    const void* W1s = d_in[3];
    const void* W1d = d_in[4];
    const void* b1s = d_in[5];
    const void* b1d = d_in[6];
    const void* W2s = d_in[7];
    const void* W2d = d_in[8];
    const void* b2s = d_in[9];
    const void* b2d = d_in[10];
    const void* Wro = d_in[11];
    const void* bro = d_in[12];
    (void)in_sizes; (void)n_in; (void)out_size; (void)d_ws; (void)ws_size;

    const int NB2 = cdiv(NE2, 1024); // 489

    init_all<<<cdiv(N_NODES * 128 / 8, 256), 256, 0, stream>>>(
        (const uint_t*)x, eidx, (const float*)x);
    edge_cnt<<<cdiv(N_EDGES, 256), 256, 0, stream>>>(
        eidx, (const ushort_t*)theta, (const float*)theta);
    scan1<<<NB2, 1024, 0, stream>>>();
    scan23<<<NB2, 256, 0, stream>>>();
    fill_all<<<cdiv(N_EDGES, 256), 256, 0, stream>>>();
    deg_pass<<<cdiv(N_NODES, 256), 256, 0, stream>>>();
    finalize_w<<<cdiv(CSR_E, 256), 256, 0, stream>>>();
    prep_all<<<cdiv(2 * 32768 + 8192, 256), 256, 0, stream>>>(
        (const ushort_t*)W1s, (const float*)W1s, (const ushort_t*)W1d, (const float*)W1d,
        (const ushort_t*)b1s, (const float*)b1s, (const ushort_t*)b1d, (const float*)b1d,
        (const ushort_t*)W2s, (const float*)W2s, (const ushort_t*)W2d, (const float*)W2d,
        (const ushort_t*)b2s, (const float*)b2s, (const ushort_t*)b2d, (const float*)b2d,
        (const ushort_t*)Wro, (const float*)Wro, (const ushort_t*)bro, (const float*)bro);

    const int AB = N_NODES / 16; // 3125 blocks, 16 nodes each (exact)
    fused_layer<0><<<AB, 256, 0, stream>>>((const ushort_t*)x, nullptr);
    fused_layer<1><<<AB, 256, 0, stream>>>(nullptr, d_out);
}